// Round 4
// baseline (3189.000 us; speedup 1.0000x reference)
//
#include <hip/hip_runtime.h>
#include <hip/hip_bf16.h>

typedef __hip_bfloat16 bf16;
typedef _Float16 h16;
typedef __attribute__((ext_vector_type(8))) _Float16 half8;
typedef __attribute__((ext_vector_type(4))) float f32x4;

#define NQ 128
#define HD 512
#define FD 256
#define NC 6
#define IMH 48
#define IMW 120
#define HW 5760   // 48*120

// ---------------------------------------------------------------------------
// Transpose features (NC, FD, HW) f32  ->  (NC, HW, FD) bf16
// ---------------------------------------------------------------------------
__global__ __launch_bounds__(256) void transpose_feat_k(const float* __restrict__ f,
                                                        bf16* __restrict__ ft)
{
    __shared__ float tile[32][33];
    int cam = blockIdx.z;
    int hw0 = blockIdx.x * 32, fd0 = blockIdx.y * 32;
    int tx = threadIdx.x, ty = threadIdx.y;
    const float* fb = f + (size_t)cam * FD * HW;
    for (int r = ty; r < 32; r += 8)
        tile[r][tx] = fb[(size_t)(fd0 + r) * HW + hw0 + tx];
    __syncthreads();
    bf16* fo = ft + (size_t)cam * HW * FD;
    for (int r = ty; r < 32; r += 8)
        fo[(size_t)(hw0 + r) * FD + fd0 + tx] = __float2bfloat16(tile[tx][r]);
}

// fp32 -> fp16 copy (for queries0 at layer 0)
__global__ __launch_bounds__(256) void cvt16_k(const float* __restrict__ src,
                                               h16* __restrict__ dst, int n)
{
    int i = blockIdx.x * 256 + threadIdx.x;
    if (i < n) dst[i] = (h16)src[i];
}

// ---------------------------------------------------------------------------
// Register-fragment MFMA GEMM, no LDS, no atomics.
// C[m][n] = sum_k actA(A[m][k]) * W[n][k] + bias[n] (+ R[m][n])
// M = 128 (or 64 per block when gridDim.y==2). Tile N = 64 per block.
// 256 thr = 4 waves; wave w owns rows mw..mw+16*nrb-1 (nrb = 2 if gridDim.y==1).
// A: fp16 in global (half8 frag loads). W: fp32 in global, cvt in-register.
// Optional: 3-section weight select (heads), A2 switch at bx>=8 (fa merged),
// nsumA slabs summed during A-load (fmlp1 camera aggregation).
// ---------------------------------------------------------------------------
__device__ __forceinline__ half8 pack8(float4 x, float4 y) {
    half8 h;
    h[0] = (h16)x.x; h[1] = (h16)x.y; h[2] = (h16)x.z; h[3] = (h16)x.w;
    h[4] = (h16)y.x; h[5] = (h16)y.y; h[6] = (h16)y.z; h[7] = (h16)y.w;
    return h;
}

__device__ __forceinline__ half8 relu8(half8 a) {
    h16 z = (h16)0.f;
#pragma unroll
    for (int e = 0; e < 8; e++) a[e] = (a[e] > z) ? a[e] : z;
    return a;
}

__global__ __launch_bounds__(256) void gemm_rf(
    const h16* __restrict__ A, const h16* __restrict__ A2, int lda,
    int nsumA, int sumStride,
    const float* __restrict__ W0, const float* __restrict__ W1, const float* __restrict__ W2s,
    const float* __restrict__ B0, const float* __restrict__ B1, const float* __restrict__ B2s,
    const float* __restrict__ R, int ldr,
    float* __restrict__ C32, h16* __restrict__ C16, int ldc,
    int K, int reluA)
{
    int bx = blockIdx.x;
    int tid = threadIdx.x, w = tid >> 6, l = tid & 63;
    int nrb = (gridDim.y == 1) ? 2 : 1;
    int m0 = blockIdx.y * 64;
    int mw = m0 + w * 16 * nrb;

    const float* Wsel = W0; const float* Bsel = B0; int nloc0 = bx * 64;
    if (W1) {
        int sec = bx >> 3;
        if (sec == 1)      { Wsel = W1;  Bsel = B1;  }
        else if (sec == 2) { Wsel = W2s; Bsel = B2s; }
        nloc0 = (bx & 7) * 64;
    }
    const h16* Ai = (A2 && bx >= 8) ? A2 : A;

    int kb = (l >> 4) * 8;
    const h16* Ap0 = Ai + (size_t)(mw + (l & 15)) * lda + kb;
    const h16* Ap1 = Ap0 + (size_t)16 * lda;
    const float* Wp[4];
#pragma unroll
    for (int ct = 0; ct < 4; ct++)
        Wp[ct] = Wsel + (size_t)(nloc0 + ct * 16 + (l & 15)) * K + kb;

    f32x4 acc[2][4];
#pragma unroll
    for (int rb = 0; rb < 2; rb++)
#pragma unroll
        for (int ct = 0; ct < 4; ct++)
            acc[rb][ct] = (f32x4){0.f, 0.f, 0.f, 0.f};

    int SG = K / 32;
#pragma unroll 2
    for (int sg = 0; sg < SG; sg++) {
        int ko = sg * 32;
        half8 a0, a1;
        if (nsumA == 1) {
            a0 = *(const half8*)(Ap0 + ko);
            if (nrb == 2) a1 = *(const half8*)(Ap1 + ko);
        } else {
            float s0[8] = {0,0,0,0,0,0,0,0}, s1[8] = {0,0,0,0,0,0,0,0};
            for (int j = 0; j < nsumA; j++) {
                half8 t0 = *(const half8*)(Ap0 + (size_t)j * sumStride + ko);
                half8 t1 = *(const half8*)(Ap1 + (size_t)j * sumStride + ko);
#pragma unroll
                for (int e = 0; e < 8; e++) { s0[e] += (float)t0[e]; s1[e] += (float)t1[e]; }
            }
#pragma unroll
            for (int e = 0; e < 8; e++) { a0[e] = (h16)s0[e]; a1[e] = (h16)s1[e]; }
        }
        if (reluA) { a0 = relu8(a0); if (nrb == 2) a1 = relu8(a1); }
#pragma unroll
        for (int ct = 0; ct < 4; ct++) {
            float4 f0 = *(const float4*)(Wp[ct] + ko);
            float4 f1 = *(const float4*)(Wp[ct] + ko + 4);
            half8 b = pack8(f0, f1);
            acc[0][ct] = __builtin_amdgcn_mfma_f32_16x16x32_f16(a0, b, acc[0][ct], 0, 0, 0);
            if (nrb == 2)
                acc[1][ct] = __builtin_amdgcn_mfma_f32_16x16x32_f16(a1, b, acc[1][ct], 0, 0, 0);
        }
    }

    int quad = l >> 4, cn = l & 15;
    int ng0 = bx * 64;
#pragma unroll
    for (int ct = 0; ct < 4; ct++) {
        int nl = nloc0 + ct * 16 + cn;
        int nc = ng0 + ct * 16 + cn;
        float bv = Bsel[nl];
        for (int rb = 0; rb < nrb; rb++) {
#pragma unroll
            for (int r = 0; r < 4; r++) {
                int m = mw + rb * 16 + quad * 4 + r;
                float v = acc[rb][ct][r] + bv;
                if (R) v += R[(size_t)m * ldr + nc];
                if (C32) C32[(size_t)m * ldc + nc] = v;
                if (C16) C16[(size_t)m * ldc + nc] = (h16)v;
            }
        }
    }
}

// ---------------------------------------------------------------------------
// Head output: out[q][n] = act( relu(hid16_row) . w2_row + b ), into d_out
// hid16 layout: [128][1536] = [motion|type|attr] halves
// ---------------------------------------------------------------------------
__global__ __launch_bounds__(64) void heads2_k(const h16* __restrict__ hid16,
                                               const float* __restrict__ w2m, const float* __restrict__ b2m,
                                               const float* __restrict__ w2t, const float* __restrict__ b2t,
                                               const float* __restrict__ w2a, const float* __restrict__ b2a,
                                               const float* __restrict__ pmin, const float* __restrict__ pmax,
                                               float* __restrict__ out)
{
    int q = blockIdx.x, n = blockIdx.y, lane = threadIdx.x;
    const float* wr; float bv; int mode, sect;
    if (n < 11)      { sect = 0; wr = w2m + n * 512;        bv = b2m[n];      mode = 0; }
    else if (n < 21) { sect = 1; wr = w2t + (n - 11) * 512; bv = b2t[n - 11]; mode = 1; }
    else             { sect = 2; wr = w2a + (n - 21) * 512; bv = b2a[n - 21]; mode = 2; }
    half8 hv = *(const half8*)(hid16 + q * 1536 + sect * 512 + lane * 8);
    const float4* w4 = (const float4*)(wr + lane * 8);
    float4 c0 = w4[0], c1 = w4[1];
    float a[8];
#pragma unroll
    for (int e = 0; e < 8; e++) a[e] = fmaxf((float)hv[e], 0.f);
    float acc = a[0] * c0.x + a[1] * c0.y + a[2] * c0.z + a[3] * c0.w
              + a[4] * c1.x + a[5] * c1.y + a[6] * c1.z + a[7] * c1.w;
    for (int off = 32; off; off >>= 1) acc += __shfl_xor(acc, off);
    if (lane == 0) {
        float v = acc + bv;
        if (mode == 0)      v = (1.0f / (1.0f + __expf(-v))) * (pmax[n] - pmin[n]) + pmin[n];
        else if (mode == 2) v = 1.0f / (1.0f + __expf(-v));
        out[q * 24 + n] = v;
    }
}

// ---------------------------------------------------------------------------
// LayerNorm over 512 dims, one block per row; dual fp32/fp16 output
// ---------------------------------------------------------------------------
__global__ __launch_bounds__(256) void ln_k(const float* __restrict__ in,
                                            const float* __restrict__ g,
                                            const float* __restrict__ b,
                                            float* __restrict__ out32,
                                            h16* __restrict__ out16)
{
    int row = blockIdx.x, tid = threadIdx.x;
    float v0 = in[row * 512 + tid];
    float v1 = in[row * 512 + tid + 256];
    float s = v0 + v1, s2 = v0 * v0 + v1 * v1;
    for (int off = 32; off; off >>= 1) { s += __shfl_xor(s, off); s2 += __shfl_xor(s2, off); }
    __shared__ float sh[8];
    if ((tid & 63) == 0) { sh[tid >> 6] = s; sh[4 + (tid >> 6)] = s2; }
    __syncthreads();
    s  = sh[0] + sh[1] + sh[2] + sh[3];
    s2 = sh[4] + sh[5] + sh[6] + sh[7];
    float mean = s * (1.0f / 512.0f);
    float var  = s2 * (1.0f / 512.0f) - mean * mean;
    float rs = rsqrtf(var + 1e-5f);
    float o0 = (v0 - mean) * rs * g[tid] + b[tid];
    float o1 = (v1 - mean) * rs * g[tid + 256] + b[tid + 256];
    out32[row * 512 + tid]       = o0;
    out32[row * 512 + tid + 256] = o1;
    out16[row * 512 + tid]       = (h16)o0;
    out16[row * 512 + tid + 256] = (h16)o1;
}

// ---------------------------------------------------------------------------
// MHA core on packed qkv (128 x 1536 = [Q|K|V] fp32), fp16 output.
// ---------------------------------------------------------------------------
__global__ __launch_bounds__(256) void attn_k(const float* __restrict__ qkv,
                                              h16* __restrict__ out16)
{
    __shared__ float KVl[128 * 68];   // K[128][68]; later reused as Vt[64][132]
    __shared__ float Ql[32 * 68];
    __shared__ float Pl[32 * 128];
    int h = blockIdx.x >> 2, chunk = blockIdx.x & 3;
    int tid = threadIdx.x;

    for (int l = tid; l < 2048; l += 256) {            // K: 128 rows x 16 float4
        int row = l >> 4, c4 = (l & 15) * 4;
        float4 v = *(const float4*)&qkv[row * 1536 + 512 + h * 64 + c4];
        *(float4*)&KVl[row * 68 + c4] = v;
    }
    for (int l = tid; l < 512; l += 256) {             // Q: 32 rows x 16 float4
        int row = l >> 4, c4 = (l & 15) * 4;
        float4 v = *(const float4*)&qkv[(chunk * 32 + row) * 1536 + h * 64 + c4];
        *(float4*)&Ql[row * 68 + c4] = v;
    }
    __syncthreads();

    int w = tid >> 6, j = tid & 63;
    for (int r8 = 0; r8 < 8; r8++) {
        int lr = w * 8 + r8;
        float s0 = 0.f, s1 = 0.f;
#pragma unroll
        for (int k4 = 0; k4 < 64; k4 += 4) {
            float4 qv  = *(const float4*)&Ql[lr * 68 + k4];
            float4 k0v = *(const float4*)&KVl[j * 68 + k4];
            float4 k1v = *(const float4*)&KVl[(j + 64) * 68 + k4];
            s0 += qv.x * k0v.x + qv.y * k0v.y + qv.z * k0v.z + qv.w * k0v.w;
            s1 += qv.x * k1v.x + qv.y * k1v.y + qv.z * k1v.z + qv.w * k1v.w;
        }
        s0 *= 0.125f; s1 *= 0.125f;
        float m = fmaxf(s0, s1);
        for (int off = 32; off; off >>= 1) m = fmaxf(m, __shfl_xor(m, off));
        float e0 = __expf(s0 - m), e1 = __expf(s1 - m);
        float sm = e0 + e1;
        for (int off = 32; off; off >>= 1) sm += __shfl_xor(sm, off);
        float inv = 1.0f / sm;
        Pl[lr * 128 + j]      = e0 * inv;
        Pl[lr * 128 + j + 64] = e1 * inv;
    }
    __syncthreads();

    for (int l = tid; l < 2048; l += 256) {            // V transposed: Vt[d][row]
        int row = l >> 4, c4 = (l & 15) * 4;
        float4 v = *(const float4*)&qkv[row * 1536 + 1024 + h * 64 + c4];
        KVl[(c4 + 0) * 132 + row] = v.x;
        KVl[(c4 + 1) * 132 + row] = v.y;
        KVl[(c4 + 2) * 132 + row] = v.z;
        KVl[(c4 + 3) * 132 + row] = v.w;
    }
    __syncthreads();

    int d = tid & 63, w2 = tid >> 6;
    for (int r8 = 0; r8 < 8; r8++) {
        int lr = w2 * 8 + r8;
        float o = 0.f;
#pragma unroll
        for (int j4 = 0; j4 < 128; j4 += 4) {
            float4 pv = *(const float4*)&Pl[lr * 128 + j4];
            float4 vv = *(const float4*)&KVl[d * 132 + j4];
            o += pv.x * vv.x + pv.y * vv.y + pv.z * vv.z + pv.w * vv.w;
        }
        out16[(chunk * 32 + lr) * 512 + h * 64 + d] = (h16)o;
    }
}

// ---------------------------------------------------------------------------
// Gather: grid (128 queries, 6 cams), 256 threads. Compacted taps, fp16 slab
// output agg16[cam][128][256] (plain stores; fmlp1 sums the 6 slabs).
// ---------------------------------------------------------------------------
__device__ __forceinline__ float bflo(unsigned u) {
    union { unsigned i; float f; } c; c.i = u << 16; return c.f;
}
__device__ __forceinline__ float bfhi(unsigned u) {
    union { unsigned i; float f; } c; c.i = u & 0xffff0000u; return c.f;
}

__global__ __launch_bounds__(256) void gather_k(const bf16* __restrict__ ft,
                                                const float* __restrict__ proj,
                                                const float* __restrict__ preds,
                                                h16* __restrict__ agg16)
{
    __shared__ float mo[11];
    __shared__ int   goff[384];
    __shared__ float gw[384];
    __shared__ int   cnt;
    __shared__ float part[8][256];
    int n = blockIdx.x, cam = blockIdx.y, tid = threadIdx.x;
    if (tid == 0) cnt = 0;
    if (tid < 11) mo[tid] = preds[n * 24 + tid];
    __syncthreads();

    if (tid < 96) {
        int p = tid;
        float dd0 = mo[8], dd1 = mo[9], dd2 = mo[10];
        float c0 = mo[0], c1 = mo[1], c2 = mo[2];
        float sy, cy;
        sincosf(mo[7], &sy, &cy);
        int face = p >> 4, axis = face >> 1;
        float sgn = (face & 1) ? 0.5f : -0.5f;
        float offi = -0.4f + (float)((p >> 2) & 3) * (0.8f / 3.0f);
        float offj = -0.4f + (float)(p & 3) * (0.8f / 3.0f);
        float t0, t1, t2;
        if (axis == 0)      { t0 = sgn;  t1 = offi; t2 = offj; }
        else if (axis == 1) { t0 = offi; t1 = sgn;  t2 = offj; }
        else                { t0 = offi; t1 = offj; t2 = sgn;  }
        float px = t0 * dd0, py = t1 * dd1, pz = t2 * dd2;
        float X = px * cy - py * sy + c0;
        float Y = px * sy + py * cy + c1;
        float Z = pz + c2;
        const float* P = proj + cam * 12;
        float cu = P[0] * X + P[1] * Y + P[2] * Z + P[3];
        float cv = P[4] * X + P[5] * Y + P[6] * Z + P[7];
        float cz = P[8] * X + P[9] * Y + P[10] * Z + P[11];
        float zs = (fabsf(cz) > 1e-6f) ? cz : 1e-6f;
        float u = cu / zs, v = cv / zs;
        bool front = cz > 0.0f;
        float u0 = floorf(u), v0 = floorf(v);
        float du = u - u0, dv = v - v0;
        float us[4] = {u0, u0 + 1.0f, u0, u0 + 1.0f};
        float vs[4] = {v0, v0, v0 + 1.0f, v0 + 1.0f};
        float wt[4] = {(1.0f - du) * (1.0f - dv), du * (1.0f - dv),
                       (1.0f - du) * dv, du * dv};
        int   myoff[4]; float myw[4]; int k = 0;
#pragma unroll
        for (int t = 0; t < 4; t++) {
            bool ok = front && (us[t] >= 0.0f) && (us[t] <= 119.0f)
                            && (vs[t] >= 0.0f) && (vs[t] <= 47.0f)
                            && (wt[t] > 0.0f);
            if (ok) {
                myoff[k] = ((int)vs[t] * IMW + (int)us[t]) * FD;
                myw[k]   = wt[t];
                k++;
            }
        }
        if (k) {
            int base = atomicAdd(&cnt, k);
            for (int s = 0; s < k; s++) { goff[base + s] = myoff[s]; gw[base + s] = myw[s]; }
        }
    }
    __syncthreads();
    int C = cnt;
    h16* slab = agg16 + (size_t)cam * 32768 + n * 256;
    if (C == 0) { slab[tid] = (h16)0.f; return; }

    int g8  = (tid & 31) * 8;
    int row = tid >> 5;
    const bf16* fb = ft + (size_t)cam * HW * FD + g8;
    float acc[8] = {0.f, 0.f, 0.f, 0.f, 0.f, 0.f, 0.f, 0.f};
    for (int e = row; e < C; e += 8) {
        float w = gw[e];
        uint4 rv = *(const uint4*)(fb + goff[e]);
        acc[0] += w * bflo(rv.x); acc[1] += w * bfhi(rv.x);
        acc[2] += w * bflo(rv.y); acc[3] += w * bfhi(rv.y);
        acc[4] += w * bflo(rv.z); acc[5] += w * bfhi(rv.z);
        acc[6] += w * bflo(rv.w); acc[7] += w * bfhi(rv.w);
    }
#pragma unroll
    for (int j = 0; j < 8; j++) part[row][g8 + j] = acc[j];
    __syncthreads();
    float s = 0.f;
#pragma unroll
    for (int r = 0; r < 8; r++) s += part[r][tid];
    slab[tid] = (h16)(s * (1.0f / 576.0f));
}

// ---------------------------------------------------------------------------
extern "C" void kernel_launch(void* const* d_in, const int* in_sizes, int n_in,
                              void* d_out, int out_size, void* d_ws, size_t ws_size,
                              hipStream_t stream)
{
    const float* features  = (const float*)d_in[0];
    const float* proj      = (const float*)d_in[1];
    const float* queries0  = (const float*)d_in[3];
    const float* pmin      = (const float*)d_in[4];
    const float* pmax      = (const float*)d_in[5];
    const float* motion_w1 = (const float*)d_in[6];
    const float* motion_b1 = (const float*)d_in[7];
    const float* motion_w2 = (const float*)d_in[8];
    const float* motion_b2 = (const float*)d_in[9];
    const float* type_w1   = (const float*)d_in[10];
    const float* type_b1   = (const float*)d_in[11];
    const float* type_w2   = (const float*)d_in[12];
    const float* type_b2   = (const float*)d_in[13];
    const float* attr_w1   = (const float*)d_in[14];
    const float* attr_b1   = (const float*)d_in[15];
    const float* attr_w2   = (const float*)d_in[16];
    const float* attr_b2   = (const float*)d_in[17];
    const float* fmlp_w1   = (const float*)d_in[18];
    const float* fmlp_b1   = (const float*)d_in[19];
    const float* fmlp_w2   = (const float*)d_in[20];
    const float* fmlp_b2   = (const float*)d_in[21];
    const float* sa_in_w   = (const float*)d_in[22];
    const float* sa_in_b   = (const float*)d_in[23];
    const float* sa_out_w  = (const float*)d_in[24];
    const float* sa_out_b  = (const float*)d_in[25];
    const float* fa_in_w   = (const float*)d_in[26];
    const float* fa_in_b   = (const float*)d_in[27];
    const float* fa_out_w  = (const float*)d_in[28];
    const float* fa_out_b  = (const float*)d_in[29];
    const float* ffn_w1    = (const float*)d_in[30];
    const float* ffn_b1    = (const float*)d_in[31];
    const float* ffn_w2    = (const float*)d_in[32];
    const float* ffn_b2    = (const float*)d_in[33];
    const float* ln1_g     = (const float*)d_in[34];
    const float* ln1_b     = (const float*)d_in[35];
    const float* ln2_g     = (const float*)d_in[36];
    const float* ln2_b     = (const float*)d_in[37];
    const float* ln3_g     = (const float*)d_in[38];
    const float* ln3_b     = (const float*)d_in[39];
    float* out = (float*)d_out;

    // workspace layout
    char* p = (char*)d_ws;
    bf16* feat_t = (bf16*)p;      p += (size_t)NC * HW * FD * 2;   // 17,694,720 B
    h16* q016    = (h16*)p;       p += 65536 * 2;
    h16* hid16   = (h16*)p;       p += 196608 * 2;
    h16* agg16   = (h16*)p;       p += 196608 * 2;
    h16* fmlph16 = (h16*)p;       p += 65536 * 2;
    h16* feath16 = (h16*)p;       p += 65536 * 2;
    h16* attnb16 = (h16*)p;       p += 65536 * 2;
    h16* lnx16   = (h16*)p;       p += 65536 * 2;
    h16* ffnh16  = (h16*)p;       p += 262144 * 2;
    h16* qn16    = (h16*)p;       p += 65536 * 2;
    float* qkv   = (float*)p;     p += 196608 * 4;
    float* lnx32 = (float*)p;     p += 65536 * 4;
    float* x1    = (float*)p;     p += 65536 * 4;
    float* x2    = (float*)p;     p += 65536 * 4;
    float* qn32  = (float*)p;     p += 65536 * 4;

    transpose_feat_k<<<dim3(180, 8, 6), dim3(32, 8), 0, stream>>>(features, feat_t);
    cvt16_k<<<256, 256, 0, stream>>>(queries0, q016, 65536);

    for (int i = 0; i < 6; i++) {
        const h16*   q16 = (i == 0) ? q016 : qn16;
        const float* q32 = (i == 0) ? queries0 : qn32;

        // prediction heads: hidden (3 sections in one dispatch) + output
        gemm_rf<<<24, 256, 0, stream>>>(q16, nullptr, 512, 1, 0,
                                        motion_w1, type_w1, attr_w1,
                                        motion_b1, type_b1, attr_b1,
                                        nullptr, 0, nullptr, hid16, 1536, 512, 0);
        heads2_k<<<dim3(128, 24), 64, 0, stream>>>(hid16, motion_w2, motion_b2,
                                                   type_w2, type_b2, attr_w2, attr_b2,
                                                   pmin, pmax, out + i * 3072);
        if (i == 5) break;

        // feature gather + feature MLP
        gather_k<<<dim3(128, 6), 256, 0, stream>>>(feat_t, proj, out + i * 3072, agg16);
        gemm_rf<<<8, 256, 0, stream>>>(agg16, nullptr, 256, 6, 32768,
                                       fmlp_w1, nullptr, nullptr,
                                       fmlp_b1, nullptr, nullptr,
                                       nullptr, 0, nullptr, fmlph16, 512, 256, 0);
        gemm_rf<<<8, 256, 0, stream>>>(fmlph16, nullptr, 512, 1, 0,
                                       fmlp_w2, nullptr, nullptr,
                                       fmlp_b2, nullptr, nullptr,
                                       nullptr, 0, nullptr, feath16, 512, 512, 1);

        // self-attention
        ln_k<<<128, 256, 0, stream>>>(q32, ln1_g + i * 512, ln1_b + i * 512, lnx32, lnx16);
        gemm_rf<<<24, 256, 0, stream>>>(lnx16, nullptr, 512, 1, 0,
                                        sa_in_w + (size_t)i * 786432, nullptr, nullptr,
                                        sa_in_b + i * 1536, nullptr, nullptr,
                                        nullptr, 0, qkv, nullptr, 1536, 512, 0);
        attn_k<<<32, 256, 0, stream>>>(qkv, attnb16);
        gemm_rf<<<8, 256, 0, stream>>>(attnb16, nullptr, 512, 1, 0,
                                       sa_out_w + (size_t)i * 262144, nullptr, nullptr,
                                       sa_out_b + i * 512, nullptr, nullptr,
                                       lnx32, 512, x1, nullptr, 512, 512, 0);

        // cross-attention (merged q/kv input projection)
        ln_k<<<128, 256, 0, stream>>>(x1, ln2_g + i * 512, ln2_b + i * 512, lnx32, lnx16);
        gemm_rf<<<24, 256, 0, stream>>>(lnx16, feath16, 512, 1, 0,
                                        fa_in_w + (size_t)i * 786432, nullptr, nullptr,
                                        fa_in_b + i * 1536, nullptr, nullptr,
                                        nullptr, 0, qkv, nullptr, 1536, 512, 0);
        attn_k<<<32, 256, 0, stream>>>(qkv, attnb16);
        gemm_rf<<<8, 256, 0, stream>>>(attnb16, nullptr, 512, 1, 0,
                                       fa_out_w + (size_t)i * 262144, nullptr, nullptr,
                                       fa_out_b + i * 512, nullptr, nullptr,
                                       lnx32, 512, x2, nullptr, 512, 512, 0);

        // FFN
        ln_k<<<128, 256, 0, stream>>>(x2, ln3_g + i * 512, ln3_b + i * 512, lnx32, lnx16);
        gemm_rf<<<32, 256, 0, stream>>>(lnx16, nullptr, 512, 1, 0,
                                        ffn_w1 + (size_t)i * 1048576, nullptr, nullptr,
                                        ffn_b1 + i * 2048, nullptr, nullptr,
                                        nullptr, 0, nullptr, ffnh16, 2048, 512, 0);
        gemm_rf<<<dim3(8, 2), 256, 0, stream>>>(ffnh16, nullptr, 2048, 1, 0,
                                                ffn_w2 + (size_t)i * 1048576, nullptr, nullptr,
                                                ffn_b2 + i * 512, nullptr, nullptr,
                                                lnx32, 512, qn32, qn16, 512, 2048, 1);
    }
}

// Round 5
// 1201.010 us; speedup vs baseline: 2.6553x; 2.6553x over previous
//
#include <hip/hip_runtime.h>
#include <hip/hip_bf16.h>

typedef __hip_bfloat16 bf16;
typedef _Float16 h16;
typedef __attribute__((ext_vector_type(8))) _Float16 half8;
typedef __attribute__((ext_vector_type(4))) float f32x4;

#define NQ 128
#define HD 512
#define FD 256
#define NC 6
#define IMH 48
#define IMW 120
#define HW 5760   // 48*120

// ---------------------------------------------------------------------------
// Transpose features (NC, FD, HW) f32  ->  (NC, HW, FD) bf16
// ---------------------------------------------------------------------------
__global__ __launch_bounds__(256) void transpose_feat_k(const float* __restrict__ f,
                                                        bf16* __restrict__ ft)
{
    __shared__ float tile[32][33];
    int cam = blockIdx.z;
    int hw0 = blockIdx.x * 32, fd0 = blockIdx.y * 32;
    int tx = threadIdx.x, ty = threadIdx.y;
    const float* fb = f + (size_t)cam * FD * HW;
    for (int r = ty; r < 32; r += 8)
        tile[r][tx] = fb[(size_t)(fd0 + r) * HW + hw0 + tx];
    __syncthreads();
    bf16* fo = ft + (size_t)cam * HW * FD;
    for (int r = ty; r < 32; r += 8)
        fo[(size_t)(hw0 + r) * FD + fd0 + tx] = __float2bfloat16(tile[tx][r]);
}

// ---------------------------------------------------------------------------
// Full-K LDS-staged MFMA GEMM. No split-K, no atomics, no memsets.
// C[m][n] = act( sum_k A[m][k]*W[n][k] + bias[n] ) (+ R[m][n])
// Grid (N/64, M/64); block 256 = 4 waves; each wave: 16 rows x 64 cols.
// K processed in 128-wide slices staged to LDS (fp32->fp16, fragment-major:
// frag (kstep s, rowblk b) at [(s*4+b)*64 + lane]*8 halfs -> conflict-free
// ds_read_b128). Slice s+1's global loads prefetch into registers while
// slice s computes (overlaps HBM/L2 latency with MFMA+ds_read).
// Options: 3-section weight select (heads, W1!=null), A2 switch at bx>=8
// (merged cross-attn q/kv), nsum>1 sums slabs during A-staging (fmlp1).
// ---------------------------------------------------------------------------
__device__ __forceinline__ void stash16(h16* dst, int rb, int lo, int kc,
                                        float4 x, float4 y)
{
    int s = kc >> 2, hi = kc & 3;
    half8 h;
    h[0] = (h16)x.x; h[1] = (h16)x.y; h[2] = (h16)x.z; h[3] = (h16)x.w;
    h[4] = (h16)y.x; h[5] = (h16)y.y; h[6] = (h16)y.z; h[7] = (h16)y.w;
    *(half8*)&dst[(size_t)(((s * 4 + rb) * 64 + hi * 16 + lo)) * 8] = h;
}

__global__ __launch_bounds__(256) void gemm_full(
    const float* __restrict__ A, const float* __restrict__ A2, int lda,
    int nsum, int sumStride,
    const float* __restrict__ W0, const float* __restrict__ W1, const float* __restrict__ W2s,
    const float* __restrict__ B0, const float* __restrict__ B1, const float* __restrict__ B2s,
    const float* __restrict__ R, int ldr,
    float* __restrict__ C, int ldc, int K, int act)
{
    __shared__ h16 Al[8192];   // 64 rows x 128 k (fragment-major)
    __shared__ h16 Bl[8192];
    int bx = blockIdx.x;
    int tid = threadIdx.x;
    int m0 = blockIdx.y * 64;

    const float* Wsel = W0; const float* Bsel = B0; int nloc0 = bx * 64;
    if (W1) {
        int sec = bx >> 3;
        if (sec == 1)      { Wsel = W1;  Bsel = B1;  }
        else if (sec == 2) { Wsel = W2s; Bsel = B2s; }
        nloc0 = (bx & 7) * 64;
    }
    const float* Ai = (A2 && bx >= 8) ? A2 : A;

    int row8 = tid >> 3;            // 0..31
    int kc2  = (tid & 7) * 2;       // chunk pair: cols kc2*8 .. kc2*8+16
    const float* Ap0 = Ai + (size_t)(m0 + row8) * lda + kc2 * 8;
    const float* Ap1 = Ai + (size_t)(m0 + row8 + 32) * lda + kc2 * 8;
    const float* Wp0 = Wsel + (size_t)(nloc0 + row8) * K + kc2 * 8;
    const float* Wp1 = Wsel + (size_t)(nloc0 + row8 + 32) * K + kc2 * 8;

    int l = tid & 63, wv = tid >> 6;
    f32x4 acc[4];
#pragma unroll
    for (int ct = 0; ct < 4; ct++) acc[ct] = (f32x4){0.f, 0.f, 0.f, 0.f};

    float4 aR[2][4], wR[2][4];
    int S = K / 128;

    // prefetch slice 0
    {
        const float* aps[2] = {Ap0, Ap1};
        const float* wps[2] = {Wp0, Wp1};
#pragma unroll
        for (int rr = 0; rr < 2; rr++) {
            if (nsum == 1) {
                const float4* ap = (const float4*)aps[rr];
                aR[rr][0] = ap[0]; aR[rr][1] = ap[1]; aR[rr][2] = ap[2]; aR[rr][3] = ap[3];
            } else {
                float4 s0 = {0,0,0,0}, s1 = {0,0,0,0}, s2 = {0,0,0,0}, s3 = {0,0,0,0};
                for (int j = 0; j < nsum; j++) {
                    const float4* ap = (const float4*)(aps[rr] + (size_t)j * sumStride);
                    float4 t0 = ap[0], t1 = ap[1], t2 = ap[2], t3 = ap[3];
                    s0.x += t0.x; s0.y += t0.y; s0.z += t0.z; s0.w += t0.w;
                    s1.x += t1.x; s1.y += t1.y; s1.z += t1.z; s1.w += t1.w;
                    s2.x += t2.x; s2.y += t2.y; s2.z += t2.z; s2.w += t2.w;
                    s3.x += t3.x; s3.y += t3.y; s3.z += t3.z; s3.w += t3.w;
                }
                aR[rr][0] = s0; aR[rr][1] = s1; aR[rr][2] = s2; aR[rr][3] = s3;
            }
            const float4* wp = (const float4*)wps[rr];
            wR[rr][0] = wp[0]; wR[rr][1] = wp[1]; wR[rr][2] = wp[2]; wR[rr][3] = wp[3];
        }
    }

    for (int s = 0; s < S; s++) {
        // store current slice registers to LDS (compiler waits vmcnt here)
#pragma unroll
        for (int rr = 0; rr < 2; rr++) {
            int m = row8 + rr * 32;
            stash16(Al, m >> 4, m & 15, kc2,     aR[rr][0], aR[rr][1]);
            stash16(Al, m >> 4, m & 15, kc2 + 1, aR[rr][2], aR[rr][3]);
            stash16(Bl, m >> 4, m & 15, kc2,     wR[rr][0], wR[rr][1]);
            stash16(Bl, m >> 4, m & 15, kc2 + 1, wR[rr][2], wR[rr][3]);
        }
        __syncthreads();

        // prefetch next slice while computing this one
        if (s + 1 < S) {
            int ko = (s + 1) * 128;
            const float* aps[2] = {Ap0 + ko, Ap1 + ko};
            const float* wps[2] = {Wp0 + ko, Wp1 + ko};
#pragma unroll
            for (int rr = 0; rr < 2; rr++) {
                if (nsum == 1) {
                    const float4* ap = (const float4*)aps[rr];
                    aR[rr][0] = ap[0]; aR[rr][1] = ap[1]; aR[rr][2] = ap[2]; aR[rr][3] = ap[3];
                } else {
                    float4 s0 = {0,0,0,0}, s1 = {0,0,0,0}, s2 = {0,0,0,0}, s3 = {0,0,0,0};
                    for (int j = 0; j < nsum; j++) {
                        const float4* ap = (const float4*)(aps[rr] + (size_t)j * sumStride);
                        float4 t0 = ap[0], t1 = ap[1], t2 = ap[2], t3 = ap[3];
                        s0.x += t0.x; s0.y += t0.y; s0.z += t0.z; s0.w += t0.w;
                        s1.x += t1.x; s1.y += t1.y; s1.z += t1.z; s1.w += t1.w;
                        s2.x += t2.x; s2.y += t2.y; s2.z += t2.z; s2.w += t2.w;
                        s3.x += t3.x; s3.y += t3.y; s3.z += t3.z; s3.w += t3.w;
                    }
                    aR[rr][0] = s0; aR[rr][1] = s1; aR[rr][2] = s2; aR[rr][3] = s3;
                }
                const float4* wp = (const float4*)wps[rr];
                wR[rr][0] = wp[0]; wR[rr][1] = wp[1]; wR[rr][2] = wp[2]; wR[rr][3] = wp[3];
            }
        }

        // MFMA over this slice: 4 ksteps x 4 col-tiles
#pragma unroll
        for (int ss = 0; ss < 4; ss++) {
            half8 af = *(const half8*)&Al[(size_t)((ss * 4 + wv) * 64 + l) * 8];
#pragma unroll
            for (int ct = 0; ct < 4; ct++) {
                half8 bf = *(const half8*)&Bl[(size_t)((ss * 4 + ct) * 64 + l) * 8];
                acc[ct] = __builtin_amdgcn_mfma_f32_16x16x32_f16(af, bf, acc[ct], 0, 0, 0);
            }
        }
        __syncthreads();
    }

    int quad = l >> 4, cn = l & 15;
    int ng0 = bx * 64;
#pragma unroll
    for (int ct = 0; ct < 4; ct++) {
        int nl = nloc0 + ct * 16 + cn;
        int nc = ng0 + ct * 16 + cn;
        float bv = Bsel[nl];
#pragma unroll
        for (int r = 0; r < 4; r++) {
            int m = m0 + wv * 16 + quad * 4 + r;
            float v = acc[ct][r] + bv;
            if (act) v = fmaxf(v, 0.f);
            if (R) v += R[(size_t)m * ldr + nc];
            C[(size_t)m * ldc + nc] = v;
        }
    }
}

// ---------------------------------------------------------------------------
// Head output: out[q][n] = act( hid_row . w2_row + b ), into d_out.
// hid: 128 x 1536 row-major = [motion|type|attr] column sections (post-relu).
// ---------------------------------------------------------------------------
__global__ __launch_bounds__(64) void heads2_k(const float* __restrict__ hid,
                                               const float* __restrict__ w2m, const float* __restrict__ b2m,
                                               const float* __restrict__ w2t, const float* __restrict__ b2t,
                                               const float* __restrict__ w2a, const float* __restrict__ b2a,
                                               const float* __restrict__ pmin, const float* __restrict__ pmax,
                                               float* __restrict__ out)
{
    int q = blockIdx.x, n = blockIdx.y, lane = threadIdx.x;
    const float* wr; float bv; int mode, sect;
    if (n < 11)      { sect = 0; wr = w2m + n * 512;        bv = b2m[n];      mode = 0; }
    else if (n < 21) { sect = 1; wr = w2t + (n - 11) * 512; bv = b2t[n - 11]; mode = 1; }
    else             { sect = 2; wr = w2a + (n - 21) * 512; bv = b2a[n - 21]; mode = 2; }
    const float4* h4 = (const float4*)(hid + q * 1536 + sect * 512);
    const float4* w4 = (const float4*)wr;
    float4 a0 = h4[lane],      c0 = w4[lane];
    float4 a1 = h4[lane + 64], c1 = w4[lane + 64];
    float acc = a0.x * c0.x + a0.y * c0.y + a0.z * c0.z + a0.w * c0.w
              + a1.x * c1.x + a1.y * c1.y + a1.z * c1.z + a1.w * c1.w;
    for (int off = 32; off; off >>= 1) acc += __shfl_xor(acc, off);
    if (lane == 0) {
        float v = acc + bv;
        if (mode == 0)      v = (1.0f / (1.0f + __expf(-v))) * (pmax[n] - pmin[n]) + pmin[n];
        else if (mode == 2) v = 1.0f / (1.0f + __expf(-v));
        out[q * 24 + n] = v;
    }
}

// ---------------------------------------------------------------------------
// LayerNorm over 512 dims, one block per row
// ---------------------------------------------------------------------------
__global__ __launch_bounds__(256) void ln_k(const float* __restrict__ in,
                                            const float* __restrict__ g,
                                            const float* __restrict__ b,
                                            float* __restrict__ out)
{
    int row = blockIdx.x, tid = threadIdx.x;
    float v0 = in[row * 512 + tid];
    float v1 = in[row * 512 + tid + 256];
    float s = v0 + v1, s2 = v0 * v0 + v1 * v1;
    for (int off = 32; off; off >>= 1) { s += __shfl_xor(s, off); s2 += __shfl_xor(s2, off); }
    __shared__ float sh[8];
    if ((tid & 63) == 0) { sh[tid >> 6] = s; sh[4 + (tid >> 6)] = s2; }
    __syncthreads();
    s  = sh[0] + sh[1] + sh[2] + sh[3];
    s2 = sh[4] + sh[5] + sh[6] + sh[7];
    float mean = s * (1.0f / 512.0f);
    float var  = s2 * (1.0f / 512.0f) - mean * mean;
    float rs = rsqrtf(var + 1e-5f);
    out[row * 512 + tid]       = (v0 - mean) * rs * g[tid] + b[tid];
    out[row * 512 + tid + 256] = (v1 - mean) * rs * g[tid + 256] + b[tid + 256];
}

// ---------------------------------------------------------------------------
// MHA core on a packed qkv buffer (128 x 1536 = [Q|K|V], heads of 64 dims).
// ---------------------------------------------------------------------------
__global__ __launch_bounds__(256) void attn_k(const float* __restrict__ qkv,
                                              float* __restrict__ out)
{
    __shared__ float KVl[128 * 68];   // K[128][68]; later reused as Vt[64][132]
    __shared__ float Ql[32 * 68];
    __shared__ float Pl[32 * 128];
    int h = blockIdx.x >> 2, chunk = blockIdx.x & 3;
    int tid = threadIdx.x;

    for (int l = tid; l < 2048; l += 256) {            // K: 128 rows x 16 float4
        int row = l >> 4, c4 = (l & 15) * 4;
        float4 v = *(const float4*)&qkv[row * 1536 + 512 + h * 64 + c4];
        *(float4*)&KVl[row * 68 + c4] = v;
    }
    for (int l = tid; l < 512; l += 256) {             // Q: 32 rows x 16 float4
        int row = l >> 4, c4 = (l & 15) * 4;
        float4 v = *(const float4*)&qkv[(chunk * 32 + row) * 1536 + h * 64 + c4];
        *(float4*)&Ql[row * 68 + c4] = v;
    }
    __syncthreads();

    int w = tid >> 6, j = tid & 63;
    for (int r8 = 0; r8 < 8; r8++) {
        int lr = w * 8 + r8;
        float s0 = 0.f, s1 = 0.f;
#pragma unroll
        for (int k4 = 0; k4 < 64; k4 += 4) {
            float4 qv  = *(const float4*)&Ql[lr * 68 + k4];
            float4 k0v = *(const float4*)&KVl[j * 68 + k4];
            float4 k1v = *(const float4*)&KVl[(j + 64) * 68 + k4];
            s0 += qv.x * k0v.x + qv.y * k0v.y + qv.z * k0v.z + qv.w * k0v.w;
            s1 += qv.x * k1v.x + qv.y * k1v.y + qv.z * k1v.z + qv.w * k1v.w;
        }
        s0 *= 0.125f; s1 *= 0.125f;
        float m = fmaxf(s0, s1);
        for (int off = 32; off; off >>= 1) m = fmaxf(m, __shfl_xor(m, off));
        float e0 = __expf(s0 - m), e1 = __expf(s1 - m);
        float sm = e0 + e1;
        for (int off = 32; off; off >>= 1) sm += __shfl_xor(sm, off);
        float inv = 1.0f / sm;
        Pl[lr * 128 + j]      = e0 * inv;
        Pl[lr * 128 + j + 64] = e1 * inv;
    }
    __syncthreads();

    for (int l = tid; l < 2048; l += 256) {            // V transposed: Vt[d][row]
        int row = l >> 4, c4 = (l & 15) * 4;
        float4 v = *(const float4*)&qkv[row * 1536 + 1024 + h * 64 + c4];
        KVl[(c4 + 0) * 132 + row] = v.x;
        KVl[(c4 + 1) * 132 + row] = v.y;
        KVl[(c4 + 2) * 132 + row] = v.z;
        KVl[(c4 + 3) * 132 + row] = v.w;
    }
    __syncthreads();

    int d = tid & 63, w2 = tid >> 6;
    for (int r8 = 0; r8 < 8; r8++) {
        int lr = w2 * 8 + r8;
        float o = 0.f;
#pragma unroll
        for (int j4 = 0; j4 < 128; j4 += 4) {
            float4 pv = *(const float4*)&Pl[lr * 128 + j4];
            float4 vv = *(const float4*)&KVl[d * 132 + j4];
            o += pv.x * vv.x + pv.y * vv.y + pv.z * vv.z + pv.w * vv.w;
        }
        out[(chunk * 32 + lr) * 512 + h * 64 + d] = o;
    }
}

// ---------------------------------------------------------------------------
// Gather: grid (128 queries, 6 cams), 256 threads. Compacted taps; writes
// fp32 slab agg[cam][128][256] with plain stores (fmlp1 sums the 6 slabs).
// ---------------------------------------------------------------------------
__device__ __forceinline__ float bflo(unsigned u) {
    union { unsigned i; float f; } c; c.i = u << 16; return c.f;
}
__device__ __forceinline__ float bfhi(unsigned u) {
    union { unsigned i; float f; } c; c.i = u & 0xffff0000u; return c.f;
}

__global__ __launch_bounds__(256) void gather_k(const bf16* __restrict__ ft,
                                                const float* __restrict__ proj,
                                                const float* __restrict__ preds,
                                                float* __restrict__ agg)
{
    __shared__ float mo[11];
    __shared__ int   goff[384];
    __shared__ float gw[384];
    __shared__ int   cnt;
    __shared__ float part[8][256];
    int n = blockIdx.x, cam = blockIdx.y, tid = threadIdx.x;
    if (tid == 0) cnt = 0;
    if (tid < 11) mo[tid] = preds[n * 24 + tid];
    __syncthreads();

    if (tid < 96) {
        int p = tid;
        float dd0 = mo[8], dd1 = mo[9], dd2 = mo[10];
        float c0 = mo[0], c1 = mo[1], c2 = mo[2];
        float sy, cy;
        sincosf(mo[7], &sy, &cy);
        int face = p >> 4, axis = face >> 1;
        float sgn = (face & 1) ? 0.5f : -0.5f;
        float offi = -0.4f + (float)((p >> 2) & 3) * (0.8f / 3.0f);
        float offj = -0.4f + (float)(p & 3) * (0.8f / 3.0f);
        float t0, t1, t2;
        if (axis == 0)      { t0 = sgn;  t1 = offi; t2 = offj; }
        else if (axis == 1) { t0 = offi; t1 = sgn;  t2 = offj; }
        else                { t0 = offi; t1 = offj; t2 = sgn;  }
        float px = t0 * dd0, py = t1 * dd1, pz = t2 * dd2;
        float X = px * cy - py * sy + c0;
        float Y = px * sy + py * cy + c1;
        float Z = pz + c2;
        const float* P = proj + cam * 12;
        float cu = P[0] * X + P[1] * Y + P[2] * Z + P[3];
        float cv = P[4] * X + P[5] * Y + P[6] * Z + P[7];
        float cz = P[8] * X + P[9] * Y + P[10] * Z + P[11];
        float zs = (fabsf(cz) > 1e-6f) ? cz : 1e-6f;
        float u = cu / zs, v = cv / zs;
        bool front = cz > 0.0f;
        float u0 = floorf(u), v0 = floorf(v);
        float du = u - u0, dv = v - v0;
        float us[4] = {u0, u0 + 1.0f, u0, u0 + 1.0f};
        float vs[4] = {v0, v0, v0 + 1.0f, v0 + 1.0f};
        float wt[4] = {(1.0f - du) * (1.0f - dv), du * (1.0f - dv),
                       (1.0f - du) * dv, du * dv};
        int   myoff[4]; float myw[4]; int k = 0;
#pragma unroll
        for (int t = 0; t < 4; t++) {
            bool ok = front && (us[t] >= 0.0f) && (us[t] <= 119.0f)
                            && (vs[t] >= 0.0f) && (vs[t] <= 47.0f)
                            && (wt[t] > 0.0f);
            if (ok) {
                myoff[k] = ((int)vs[t] * IMW + (int)us[t]) * FD;
                myw[k]   = wt[t];
                k++;
            }
        }
        if (k) {
            int base = atomicAdd(&cnt, k);
            for (int s = 0; s < k; s++) { goff[base + s] = myoff[s]; gw[base + s] = myw[s]; }
        }
    }
    __syncthreads();
    int C = cnt;
    float* slab = agg + (size_t)cam * 32768 + n * 256;
    if (C == 0) { slab[tid] = 0.f; return; }

    int g8  = (tid & 31) * 8;
    int row = tid >> 5;
    const bf16* fb = ft + (size_t)cam * HW * FD + g8;
    float acc[8] = {0.f, 0.f, 0.f, 0.f, 0.f, 0.f, 0.f, 0.f};
    for (int e = row; e < C; e += 8) {
        float w = gw[e];
        uint4 rv = *(const uint4*)(fb + goff[e]);
        acc[0] += w * bflo(rv.x); acc[1] += w * bfhi(rv.x);
        acc[2] += w * bflo(rv.y); acc[3] += w * bfhi(rv.y);
        acc[4] += w * bflo(rv.z); acc[5] += w * bfhi(rv.z);
        acc[6] += w * bflo(rv.w); acc[7] += w * bfhi(rv.w);
    }
#pragma unroll
    for (int j = 0; j < 8; j++) part[row][g8 + j] = acc[j];
    __syncthreads();
    float s = 0.f;
#pragma unroll
    for (int r = 0; r < 8; r++) s += part[r][tid];
    slab[tid] = s * (1.0f / 576.0f);
}

// ---------------------------------------------------------------------------
extern "C" void kernel_launch(void* const* d_in, const int* in_sizes, int n_in,
                              void* d_out, int out_size, void* d_ws, size_t ws_size,
                              hipStream_t stream)
{
    const float* features  = (const float*)d_in[0];
    const float* proj      = (const float*)d_in[1];
    const float* queries0  = (const float*)d_in[3];
    const float* pmin      = (const float*)d_in[4];
    const float* pmax      = (const float*)d_in[5];
    const float* motion_w1 = (const float*)d_in[6];
    const float* motion_b1 = (const float*)d_in[7];
    const float* motion_w2 = (const float*)d_in[8];
    const float* motion_b2 = (const float*)d_in[9];
    const float* type_w1   = (const float*)d_in[10];
    const float* type_b1   = (const float*)d_in[11];
    const float* type_w2   = (const float*)d_in[12];
    const float* type_b2   = (const float*)d_in[13];
    const float* attr_w1   = (const float*)d_in[14];
    const float* attr_b1   = (const float*)d_in[15];
    const float* attr_w2   = (const float*)d_in[16];
    const float* attr_b2   = (const float*)d_in[17];
    const float* fmlp_w1   = (const float*)d_in[18];
    const float* fmlp_b1   = (const float*)d_in[19];
    const float* fmlp_w2   = (const float*)d_in[20];
    const float* fmlp_b2   = (const float*)d_in[21];
    const float* sa_in_w   = (const float*)d_in[22];
    const float* sa_in_b   = (const float*)d_in[23];
    const float* sa_out_w  = (const float*)d_in[24];
    const float* sa_out_b  = (const float*)d_in[25];
    const float* fa_in_w   = (const float*)d_in[26];
    const float* fa_in_b   = (const float*)d_in[27];
    const float* fa_out_w  = (const float*)d_in[28];
    const float* fa_out_b  = (const float*)d_in[29];
    const float* ffn_w1    = (const float*)d_in[30];
    const float* ffn_b1    = (const float*)d_in[31];
    const float* ffn_w2    = (const float*)d_in[32];
    const float* ffn_b2    = (const float*)d_in[33];
    const float* ln1_g     = (const float*)d_in[34];
    const float* ln1_b     = (const float*)d_in[35];
    const float* ln2_g     = (const float*)d_in[36];
    const float* ln2_b     = (const float*)d_in[37];
    const float* ln3_g     = (const float*)d_in[38];
    const float* ln3_b     = (const float*)d_in[39];
    float* out = (float*)d_out;

    // workspace layout (all fp32 activations)
    char* p = (char*)d_ws;
    bf16* feat_t = (bf16*)p;    p += (size_t)NC * HW * FD * 2;   // 17,694,720 B
    float* hid3  = (float*)p;   p += 196608 * 4;   // 128x1536 (post-relu head hiddens)
    float* agg   = (float*)p;   p += 196608 * 4;   // 6 x 128x256 camera slabs
    float* fmlph = (float*)p;   p += 65536 * 4;    // 128x512 (post-relu)
    float* feath = (float*)p;   p += 65536 * 4;    // 128x512
    float* qkv   = (float*)p;   p += 196608 * 4;   // 128x1536
    float* attnb = (float*)p;   p += 65536 * 4;    // 128x512
    float* lnx   = (float*)p;   p += 65536 * 4;    // 128x512
    float* x1    = (float*)p;   p += 65536 * 4;
    float* x2    = (float*)p;   p += 65536 * 4;
    float* ffnh  = (float*)p;   p += 262144 * 4;   // 128x2048 (post-relu)
    float* qn    = (float*)p;   p += 65536 * 4;

    transpose_feat_k<<<dim3(180, 8, 6), dim3(32, 8), 0, stream>>>(features, feat_t);

    const float* qcur = queries0;
    for (int i = 0; i < 6; i++) {
        // prediction heads: hidden (3 sections, one dispatch, relu) + output
        gemm_full<<<dim3(24, 2), 256, 0, stream>>>(qcur, nullptr, 512, 1, 0,
                                                   motion_w1, type_w1, attr_w1,
                                                   motion_b1, type_b1, attr_b1,
                                                   nullptr, 0, hid3, 1536, 512, 1);
        heads2_k<<<dim3(128, 24), 64, 0, stream>>>(hid3, motion_w2, motion_b2,
                                                   type_w2, type_b2, attr_w2, attr_b2,
                                                   pmin, pmax, out + i * 3072);
        if (i == 5) break;

        // feature gather + feature MLP (fmlp1 sums 6 camera slabs at A-stage)
        gather_k<<<dim3(128, 6), 256, 0, stream>>>(feat_t, proj, out + i * 3072, agg);
        gemm_full<<<dim3(8, 2), 256, 0, stream>>>(agg, nullptr, 256, 6, 32768,
                                                  fmlp_w1, nullptr, nullptr,
                                                  fmlp_b1, nullptr, nullptr,
                                                  nullptr, 0, fmlph, 512, 256, 1);
        gemm_full<<<dim3(8, 2), 256, 0, stream>>>(fmlph, nullptr, 512, 1, 0,
                                                  fmlp_w2, nullptr, nullptr,
                                                  fmlp_b2, nullptr, nullptr,
                                                  nullptr, 0, feath, 512, 512, 0);

        // self-attention
        ln_k<<<128, 256, 0, stream>>>(qcur, ln1_g + i * 512, ln1_b + i * 512, lnx);
        gemm_full<<<dim3(24, 2), 256, 0, stream>>>(lnx, nullptr, 512, 1, 0,
                                                   sa_in_w + (size_t)i * 786432, nullptr, nullptr,
                                                   sa_in_b + i * 1536, nullptr, nullptr,
                                                   nullptr, 0, qkv, 1536, 512, 0);
        attn_k<<<32, 256, 0, stream>>>(qkv, attnb);
        gemm_full<<<dim3(8, 2), 256, 0, stream>>>(attnb, nullptr, 512, 1, 0,
                                                  sa_out_w + (size_t)i * 262144, nullptr, nullptr,
                                                  sa_out_b + i * 512, nullptr, nullptr,
                                                  lnx, 512, x1, 512, 512, 0);

        // cross-attention (merged q/kv projection: A2 switch at bx>=8)
        ln_k<<<128, 256, 0, stream>>>(x1, ln2_g + i * 512, ln2_b + i * 512, lnx);
        gemm_full<<<dim3(24, 2), 256, 0, stream>>>(lnx, feath, 512, 1, 0,
                                                   fa_in_w + (size_t)i * 786432, nullptr, nullptr,
                                                   fa_in_b + i * 1536, nullptr, nullptr,
                                                   nullptr, 0, qkv, 1536, 512, 0);
        attn_k<<<32, 256, 0, stream>>>(qkv, attnb);
        gemm_full<<<dim3(8, 2), 256, 0, stream>>>(attnb, nullptr, 512, 1, 0,
                                                  fa_out_w + (size_t)i * 262144, nullptr, nullptr,
                                                  fa_out_b + i * 512, nullptr, nullptr,
                                                  lnx, 512, x2, 512, 512, 0);

        // FFN
        ln_k<<<128, 256, 0, stream>>>(x2, ln3_g + i * 512, ln3_b + i * 512, lnx);
        gemm_full<<<dim3(32, 2), 256, 0, stream>>>(lnx, nullptr, 512, 1, 0,
                                                   ffn_w1 + (size_t)i * 1048576, nullptr, nullptr,
                                                   ffn_b1 + i * 2048, nullptr, nullptr,
                                                   nullptr, 0, ffnh, 2048, 512, 1);
        gemm_full<<<dim3(8, 2), 256, 0, stream>>>(ffnh, nullptr, 2048, 1, 0,
                                                  ffn_w2 + (size_t)i * 1048576, nullptr, nullptr,
                                                  ffn_b2 + i * 512, nullptr, nullptr,
                                                  lnx, 512, qn, 512, 2048, 0);

        qcur = qn;
    }
}

// Round 6
// 1160.600 us; speedup vs baseline: 2.7477x; 1.0348x over previous
//
#include <hip/hip_runtime.h>
#include <hip/hip_bf16.h>

typedef __hip_bfloat16 bf16;
typedef _Float16 h16;
typedef __attribute__((ext_vector_type(8))) _Float16 half8;
typedef __attribute__((ext_vector_type(4))) float f32x4;

#define NQ 128
#define HD 512
#define FD 256
#define NC 6
#define IMH 48
#define IMW 120
#define HW 5760   // 48*120

__device__ __forceinline__ half8 pack8(float4 x, float4 y) {
    half8 h;
    h[0] = (h16)x.x; h[1] = (h16)x.y; h[2] = (h16)x.z; h[3] = (h16)x.w;
    h[4] = (h16)y.x; h[5] = (h16)y.y; h[6] = (h16)y.z; h[7] = (h16)y.w;
    return h;
}

// ---------------------------------------------------------------------------
// Transpose features (NC, FD, HW) f32  ->  (NC, HW, FD) bf16
// ---------------------------------------------------------------------------
__global__ __launch_bounds__(256) void transpose_feat_k(const float* __restrict__ f,
                                                        bf16* __restrict__ ft)
{
    __shared__ float tile[32][33];
    int cam = blockIdx.z;
    int hw0 = blockIdx.x * 32, fd0 = blockIdx.y * 32;
    int tx = threadIdx.x, ty = threadIdx.y;
    const float* fb = f + (size_t)cam * FD * HW;
    for (int r = ty; r < 32; r += 8)
        tile[r][tx] = fb[(size_t)(fd0 + r) * HW + hw0 + tx];
    __syncthreads();
    bf16* fo = ft + (size_t)cam * HW * FD;
    for (int r = ty; r < 32; r += 8)
        fo[(size_t)(hw0 + r) * FD + fd0 + tx] = __float2bfloat16(tile[tx][r]);
}

// fp32 -> fp16 copy (queries0)
__global__ __launch_bounds__(256) void cvt16_k(const float* __restrict__ src,
                                               h16* __restrict__ dst, int n)
{
    int i = blockIdx.x * 256 + threadIdx.x;
    if (i < n) dst[i] = (h16)src[i];
}

// ---------------------------------------------------------------------------
// Weight swizzle: all weights -> fp16 MFMA B-fragment order.
// Tile (n64, ks, ct): lane l holds W[n64*64 + ct*16 + (l&15)][ks*32 + (l>>4)*8 + j],
// j=0..7, stored as 64 contiguous 16B chunks (1KB per tile). Tiles packed
// linearly per weight -> dst offset = global_tile_id * 512 halfs.
// ---------------------------------------------------------------------------
struct SwzDesc {
    const float* src[11];
    unsigned int tileStart[12];
    int K[11];
};

__global__ __launch_bounds__(64) void swizzle_w_k(SwzDesc d, h16* __restrict__ dst)
{
    int bid = blockIdx.x;
    int w = 0;
    while (bid >= (int)d.tileStart[w + 1]) w++;
    int local = bid - (int)d.tileStart[w];
    int Kk = d.K[w];
    int kt4 = (Kk >> 5) << 2;          // tiles per 64-row group
    int n64 = local / kt4;
    int kt  = local - n64 * kt4;
    int ks = kt >> 2, ct = kt & 3;
    int l = threadIdx.x;
    int row = n64 * 64 + ct * 16 + (l & 15);
    int col = ks * 32 + (l >> 4) * 8;
    const float* s = d.src[w] + (size_t)row * Kk + col;
    float4 u = *(const float4*)s;
    float4 v = *(const float4*)(s + 4);
    *(half8*)(dst + ((size_t)bid * 64 + l) * 8) = pack8(u, v);
}

// ---------------------------------------------------------------------------
// Barrier-free 1-wave MFMA GEMM on swizzled fp16 weights.
// C[m][n] = act( sum_k a(A)[m][k]*W[n][k] + bias[n] ) (+ R[m][n])
// grid (N/(16*CTN), M/16), block 64 (one wave).
// B-frag: direct coalesced half8 load from swizzled weights.
// A-frag: fp16 row-major (NSUM slabs summed), or fp32 + fused LayerNorm (LNA).
// A2SW: blocks bx>=a2Start read A2 (fp16, no LN) -- merged cross-attn q/kv.
// LNA && bx==0: also writes normalized rows to lnout (for residual use).
// ---------------------------------------------------------------------------
template<int CTN, int NSUM, bool A2SW, bool LNA>
__global__ __launch_bounds__(64) void gemm_swz(
    const h16* __restrict__ A16, int lda, int sumStride,
    const float* __restrict__ A32,
    const float* __restrict__ lng, const float* __restrict__ lnb,
    float* __restrict__ lnout,
    const h16* __restrict__ A2_16, int a2Start,
    const h16* __restrict__ Wswz,
    const float* __restrict__ B0, const float* __restrict__ B1, const float* __restrict__ B2s,
    const float* __restrict__ R, int ldr,
    float* __restrict__ C32, h16* __restrict__ C16, int ldc,
    int K, int act)
{
    int bx = blockIdx.x, by = blockIdx.y;
    int l = threadIdx.x;
    int m0 = by * 16;
    int n0 = bx * 16 * CTN;
    int lr = l & 15, q4 = l >> 4;
    int row = m0 + lr;
    int K32 = K >> 5;

    bool useA2 = A2SW && (bx >= a2Start);

    float mean = 0.f, rstd = 1.f;
    const float* arow32 = A32 ? (A32 + (size_t)row * K + q4 * 8) : nullptr;
    if (LNA && !useA2) {
        float s = 0.f, s2 = 0.f;
        for (int ks = 0; ks < K32; ks++) {
            float4 u = *(const float4*)(arow32 + ks * 32);
            float4 v = *(const float4*)(arow32 + ks * 32 + 4);
            s  += u.x + u.y + u.z + u.w + v.x + v.y + v.z + v.w;
            s2 += u.x*u.x + u.y*u.y + u.z*u.z + u.w*u.w
                + v.x*v.x + v.y*v.y + v.z*v.z + v.w*v.w;
        }
        s  += __shfl_xor(s, 16);  s  += __shfl_xor(s, 32);
        s2 += __shfl_xor(s2, 16); s2 += __shfl_xor(s2, 32);
        mean = s * (1.0f / (float)K);
        float var = s2 * (1.0f / (float)K) - mean * mean;
        rstd = rsqrtf(var + 1e-5f);
    }

    const h16* arow16;
    if (useA2) arow16 = A2_16 + (size_t)row * 512 + q4 * 8;
    else       arow16 = A16 ? (A16 + (size_t)row * lda + q4 * 8) : nullptr;

    f32x4 acc[CTN];
#pragma unroll
    for (int ct = 0; ct < CTN; ct++) acc[ct] = (f32x4){0.f, 0.f, 0.f, 0.f};

    bool wrln = LNA && !useA2 && (bx == 0) && lnout;

#pragma unroll 4
    for (int ks = 0; ks < K32; ks++) {
        half8 a;
        if (LNA && !useA2) {
            float4 u = *(const float4*)(arow32 + ks * 32);
            float4 v = *(const float4*)(arow32 + ks * 32 + 4);
            float4 g0 = *(const float4*)(lng + ks * 32 + q4 * 8);
            float4 g1 = *(const float4*)(lng + ks * 32 + q4 * 8 + 4);
            float4 b0 = *(const float4*)(lnb + ks * 32 + q4 * 8);
            float4 b1 = *(const float4*)(lnb + ks * 32 + q4 * 8 + 4);
            float4 o0, o1;
            o0.x = (u.x - mean) * rstd * g0.x + b0.x;
            o0.y = (u.y - mean) * rstd * g0.y + b0.y;
            o0.z = (u.z - mean) * rstd * g0.z + b0.z;
            o0.w = (u.w - mean) * rstd * g0.w + b0.w;
            o1.x = (v.x - mean) * rstd * g1.x + b1.x;
            o1.y = (v.y - mean) * rstd * g1.y + b1.y;
            o1.z = (v.z - mean) * rstd * g1.z + b1.z;
            o1.w = (v.w - mean) * rstd * g1.w + b1.w;
            if (wrln) {
                *(float4*)(lnout + (size_t)row * K + ks * 32 + q4 * 8)     = o0;
                *(float4*)(lnout + (size_t)row * K + ks * 32 + q4 * 8 + 4) = o1;
            }
            a = pack8(o0, o1);
        } else if (NSUM == 1) {
            a = *(const half8*)(arow16 + (size_t)ks * 32);
        } else {
            float s[8] = {0.f, 0.f, 0.f, 0.f, 0.f, 0.f, 0.f, 0.f};
#pragma unroll
            for (int j = 0; j < NSUM; j++) {
                half8 t = *(const half8*)(arow16 + (size_t)j * sumStride + ks * 32);
#pragma unroll
                for (int e = 0; e < 8; e++) s[e] += (float)t[e];
            }
#pragma unroll
            for (int e = 0; e < 8; e++) a[e] = (h16)s[e];
        }
#pragma unroll
        for (int ct = 0; ct < CTN; ct++) {
            int tct = (n0 >> 4) + ct;
            const half8* bp = (const half8*)(Wswz +
                ((((size_t)(tct >> 2) * K32 + ks) * 4 + (tct & 3)) * 64 + l) * 8);
            acc[ct] = __builtin_amdgcn_mfma_f32_16x16x32_f16(a, *bp, acc[ct], 0, 0, 0);
        }
    }

    int cn = l & 15;
#pragma unroll
    for (int ct = 0; ct < CTN; ct++) {
        int n = n0 + ct * 16 + cn;
        float bv;
        if (B1) { int sec = n >> 9, ni = n & 511;
                  bv = (sec == 0) ? B0[ni] : (sec == 1 ? B1[ni] : B2s[ni]); }
        else bv = B0[n];
#pragma unroll
        for (int r = 0; r < 4; r++) {
            int m = m0 + q4 * 4 + r;
            float v = acc[ct][r] + bv;
            if (act) v = fmaxf(v, 0.f);
            if (R) v += R[(size_t)m * ldr + n];
            if (C32) C32[(size_t)m * ldc + n] = v;
            if (C16) C16[(size_t)m * ldc + n] = (h16)v;
        }
    }
}

// ---------------------------------------------------------------------------
// Head output: out[q][n] = act( hid16_row . w2_row + b ), into d_out.
// hid16: [128][1536] fp16 = [motion|type|attr] sections (post-relu).
// ---------------------------------------------------------------------------
__global__ __launch_bounds__(64) void heads2_k(const h16* __restrict__ hid16,
                                               const float* __restrict__ w2m, const float* __restrict__ b2m,
                                               const float* __restrict__ w2t, const float* __restrict__ b2t,
                                               const float* __restrict__ w2a, const float* __restrict__ b2a,
                                               const float* __restrict__ pmin, const float* __restrict__ pmax,
                                               float* __restrict__ out)
{
    int q = blockIdx.x, n = blockIdx.y, lane = threadIdx.x;
    const float* wr; float bv; int mode, sect;
    if (n < 11)      { sect = 0; wr = w2m + n * 512;        bv = b2m[n];      mode = 0; }
    else if (n < 21) { sect = 1; wr = w2t + (n - 11) * 512; bv = b2t[n - 11]; mode = 1; }
    else             { sect = 2; wr = w2a + (n - 21) * 512; bv = b2a[n - 21]; mode = 2; }
    half8 hv = *(const half8*)(hid16 + q * 1536 + sect * 512 + lane * 8);
    const float4* w4 = (const float4*)(wr + lane * 8);
    float4 c0 = w4[0], c1 = w4[1];
    float acc = (float)hv[0] * c0.x + (float)hv[1] * c0.y
              + (float)hv[2] * c0.z + (float)hv[3] * c0.w
              + (float)hv[4] * c1.x + (float)hv[5] * c1.y
              + (float)hv[6] * c1.z + (float)hv[7] * c1.w;
    for (int off = 32; off; off >>= 1) acc += __shfl_xor(acc, off);
    if (lane == 0) {
        float v = acc + bv;
        if (mode == 0)      v = (1.0f / (1.0f + __expf(-v))) * (pmax[n] - pmin[n]) + pmin[n];
        else if (mode == 2) v = 1.0f / (1.0f + __expf(-v));
        out[q * 24 + n] = v;
    }
}

// ---------------------------------------------------------------------------
// MHA core on packed qkv (128 x 1536 = [Q|K|V] fp32), fp16 output.
// ---------------------------------------------------------------------------
__global__ __launch_bounds__(256) void attn_k(const float* __restrict__ qkv,
                                              h16* __restrict__ out16)
{
    __shared__ float KVl[128 * 68];
    __shared__ float Ql[32 * 68];
    __shared__ float Pl[32 * 128];
    int h = blockIdx.x >> 2, chunk = blockIdx.x & 3;
    int tid = threadIdx.x;

    for (int l = tid; l < 2048; l += 256) {
        int row = l >> 4, c4 = (l & 15) * 4;
        float4 v = *(const float4*)&qkv[row * 1536 + 512 + h * 64 + c4];
        *(float4*)&KVl[row * 68 + c4] = v;
    }
    for (int l = tid; l < 512; l += 256) {
        int row = l >> 4, c4 = (l & 15) * 4;
        float4 v = *(const float4*)&qkv[(chunk * 32 + row) * 1536 + h * 64 + c4];
        *(float4*)&Ql[row * 68 + c4] = v;
    }
    __syncthreads();

    int w = tid >> 6, j = tid & 63;
    for (int r8 = 0; r8 < 8; r8++) {
        int lr = w * 8 + r8;
        float s0 = 0.f, s1 = 0.f;
#pragma unroll
        for (int k4 = 0; k4 < 64; k4 += 4) {
            float4 qv  = *(const float4*)&Ql[lr * 68 + k4];
            float4 k0v = *(const float4*)&KVl[j * 68 + k4];
            float4 k1v = *(const float4*)&KVl[(j + 64) * 68 + k4];
            s0 += qv.x * k0v.x + qv.y * k0v.y + qv.z * k0v.z + qv.w * k0v.w;
            s1 += qv.x * k1v.x + qv.y * k1v.y + qv.z * k1v.z + qv.w * k1v.w;
        }
        s0 *= 0.125f; s1 *= 0.125f;
        float m = fmaxf(s0, s1);
        for (int off = 32; off; off >>= 1) m = fmaxf(m, __shfl_xor(m, off));
        float e0 = __expf(s0 - m), e1 = __expf(s1 - m);
        float sm = e0 + e1;
        for (int off = 32; off; off >>= 1) sm += __shfl_xor(sm, off);
        float inv = 1.0f / sm;
        Pl[lr * 128 + j]      = e0 * inv;
        Pl[lr * 128 + j + 64] = e1 * inv;
    }
    __syncthreads();

    for (int l = tid; l < 2048; l += 256) {
        int row = l >> 4, c4 = (l & 15) * 4;
        float4 v = *(const float4*)&qkv[row * 1536 + 1024 + h * 64 + c4];
        KVl[(c4 + 0) * 132 + row] = v.x;
        KVl[(c4 + 1) * 132 + row] = v.y;
        KVl[(c4 + 2) * 132 + row] = v.z;
        KVl[(c4 + 3) * 132 + row] = v.w;
    }
    __syncthreads();

    int d = tid & 63, w2 = tid >> 6;
    for (int r8 = 0; r8 < 8; r8++) {
        int lr = w2 * 8 + r8;
        float o = 0.f;
#pragma unroll
        for (int j4 = 0; j4 < 128; j4 += 4) {
            float4 pv = *(const float4*)&Pl[lr * 128 + j4];
            float4 vv = *(const float4*)&KVl[d * 132 + j4];
            o += pv.x * vv.x + pv.y * vv.y + pv.z * vv.z + pv.w * vv.w;
        }
        out16[(chunk * 32 + lr) * 512 + h * 64 + d] = (h16)o;
    }
}

// ---------------------------------------------------------------------------
// Gather: grid (128 queries, 6 cams). Compacted taps; fp16 slab out
// agg16[cam][128][256] (plain stores; fmlp1 sums the 6 slabs).
// ---------------------------------------------------------------------------
__device__ __forceinline__ float bflo(unsigned u) {
    union { unsigned i; float f; } c; c.i = u << 16; return c.f;
}
__device__ __forceinline__ float bfhi(unsigned u) {
    union { unsigned i; float f; } c; c.i = u & 0xffff0000u; return c.f;
}

__global__ __launch_bounds__(256) void gather_k(const bf16* __restrict__ ft,
                                                const float* __restrict__ proj,
                                                const float* __restrict__ preds,
                                                h16* __restrict__ agg16)
{
    __shared__ float mo[11];
    __shared__ int   goff[384];
    __shared__ float gw[384];
    __shared__ int   cnt;
    __shared__ float part[8][256];
    int n = blockIdx.x, cam = blockIdx.y, tid = threadIdx.x;
    if (tid == 0) cnt = 0;
    if (tid < 11) mo[tid] = preds[n * 24 + tid];
    __syncthreads();

    if (tid < 96) {
        int p = tid;
        float dd0 = mo[8], dd1 = mo[9], dd2 = mo[10];
        float c0 = mo[0], c1 = mo[1], c2 = mo[2];
        float sy, cy;
        sincosf(mo[7], &sy, &cy);
        int face = p >> 4, axis = face >> 1;
        float sgn = (face & 1) ? 0.5f : -0.5f;
        float offi = -0.4f + (float)((p >> 2) & 3) * (0.8f / 3.0f);
        float offj = -0.4f + (float)(p & 3) * (0.8f / 3.0f);
        float t0, t1, t2;
        if (axis == 0)      { t0 = sgn;  t1 = offi; t2 = offj; }
        else if (axis == 1) { t0 = offi; t1 = sgn;  t2 = offj; }
        else                { t0 = offi; t1 = offj; t2 = sgn;  }
        float px = t0 * dd0, py = t1 * dd1, pz = t2 * dd2;
        float X = px * cy - py * sy + c0;
        float Y = px * sy + py * cy + c1;
        float Z = pz + c2;
        const float* P = proj + cam * 12;
        float cu = P[0] * X + P[1] * Y + P[2] * Z + P[3];
        float cv = P[4] * X + P[5] * Y + P[6] * Z + P[7];
        float cz = P[8] * X + P[9] * Y + P[10] * Z + P[11];
        float zs = (fabsf(cz) > 1e-6f) ? cz : 1e-6f;
        float u = cu / zs, v = cv / zs;
        bool front = cz > 0.0f;
        float u0 = floorf(u), v0 = floorf(v);
        float du = u - u0, dv = v - v0;
        float us[4] = {u0, u0 + 1.0f, u0, u0 + 1.0f};
        float vs[4] = {v0, v0, v0 + 1.0f, v0 + 1.0f};
        float wt[4] = {(1.0f - du) * (1.0f - dv), du * (1.0f - dv),
                       (1.0f - du) * dv, du * dv};
        int   myoff[4]; float myw[4]; int k = 0;
#pragma unroll
        for (int t = 0; t < 4; t++) {
            bool ok = front && (us[t] >= 0.0f) && (us[t] <= 119.0f)
                            && (vs[t] >= 0.0f) && (vs[t] <= 47.0f)
                            && (wt[t] > 0.0f);
            if (ok) {
                myoff[k] = ((int)vs[t] * IMW + (int)us[t]) * FD;
                myw[k]   = wt[t];
                k++;
            }
        }
        if (k) {
            int base = atomicAdd(&cnt, k);
            for (int s = 0; s < k; s++) { goff[base + s] = myoff[s]; gw[base + s] = myw[s]; }
        }
    }
    __syncthreads();
    int C = cnt;
    h16* slab = agg16 + (size_t)cam * 32768 + n * 256;
    if (C == 0) { slab[tid] = (h16)0.f; return; }

    int g8  = (tid & 31) * 8;
    int row = tid >> 5;
    const bf16* fb = ft + (size_t)cam * HW * FD + g8;
    float acc[8] = {0.f, 0.f, 0.f, 0.f, 0.f, 0.f, 0.f, 0.f};
    for (int e = row; e < C; e += 8) {
        float w = gw[e];
        uint4 rv = *(const uint4*)(fb + goff[e]);
        acc[0] += w * bflo(rv.x); acc[1] += w * bfhi(rv.x);
        acc[2] += w * bflo(rv.y); acc[3] += w * bfhi(rv.y);
        acc[4] += w * bflo(rv.z); acc[5] += w * bfhi(rv.z);
        acc[6] += w * bflo(rv.w); acc[7] += w * bfhi(rv.w);
    }
#pragma unroll
    for (int j = 0; j < 8; j++) part[row][g8 + j] = acc[j];
    __syncthreads();
    float s = 0.f;
#pragma unroll
    for (int r = 0; r < 8; r++) s += part[r][tid];
    slab[tid] = (h16)(s * (1.0f / 576.0f));
}

// ---------------------------------------------------------------------------
extern "C" void kernel_launch(void* const* d_in, const int* in_sizes, int n_in,
                              void* d_out, int out_size, void* d_ws, size_t ws_size,
                              hipStream_t stream)
{
    const float* features  = (const float*)d_in[0];
    const float* proj      = (const float*)d_in[1];
    const float* queries0  = (const float*)d_in[3];
    const float* pmin      = (const float*)d_in[4];
    const float* pmax      = (const float*)d_in[5];
    const float* motion_w1 = (const float*)d_in[6];
    const float* motion_b1 = (const float*)d_in[7];
    const float* motion_w2 = (const float*)d_in[8];
    const float* motion_b2 = (const float*)d_in[9];
    const float* type_w1   = (const float*)d_in[10];
    const float* type_b1   = (const float*)d_in[11];
    const float* type_w2   = (const float*)d_in[12];
    const float* type_b2   = (const float*)d_in[13];
    const float* attr_w1   = (const float*)d_in[14];
    const float* attr_b1   = (const float*)d_in[15];
    const float* attr_w2   = (const float*)d_in[16];
    const float* attr_b2   = (const float*)d_in[17];
    const float* fmlp_w1   = (const float*)d_in[18];
    const float* fmlp_b1   = (const float*)d_in[19];
    const float* fmlp_w2   = (const float*)d_in[20];
    const float* fmlp_b2   = (const float*)d_in[21];
    const float* sa_in_w   = (const float*)d_in[22];
    const float* sa_in_b   = (const float*)d_in[23];
    const float* sa_out_w  = (const float*)d_in[24];
    const float* sa_out_b  = (const float*)d_in[25];
    const float* fa_in_w   = (const float*)d_in[26];
    const float* fa_in_b   = (const float*)d_in[27];
    const float* fa_out_w  = (const float*)d_in[28];
    const float* fa_out_b  = (const float*)d_in[29];
    const float* ffn_w1    = (const float*)d_in[30];
    const float* ffn_b1    = (const float*)d_in[31];
    const float* ffn_w2    = (const float*)d_in[32];
    const float* ffn_b2    = (const float*)d_in[33];
    const float* ln1_g     = (const float*)d_in[34];
    const float* ln1_b     = (const float*)d_in[35];
    const float* ln2_g     = (const float*)d_in[36];
    const float* ln2_b     = (const float*)d_in[37];
    const float* ln3_g     = (const float*)d_in[38];
    const float* ln3_b     = (const float*)d_in[39];
    float* out = (float*)d_out;

    // ---- workspace ----
    char* p = (char*)d_ws;
    bf16* feat_t = (bf16*)p;   p += (size_t)NC * HW * FD * 2;        // 17.7 MB
    h16* swz     = (h16*)p;    p += (size_t)51456 * 512 * 2;         // 52.7 MB
    h16* q016    = (h16*)p;    p += 65536 * 2;
    h16* hid16   = (h16*)p;    p += 196608 * 2;
    h16* agg16   = (h16*)p;    p += 196608 * 2;
    h16* fmlph16 = (h16*)p;    p += 65536 * 2;
    h16* feath16 = (h16*)p;    p += 65536 * 2;
    h16* attnb16 = (h16*)p;    p += 65536 * 2;
    h16* ffnh16  = (h16*)p;    p += 262144 * 2;
    h16* qn16    = (h16*)p;    p += 65536 * 2;
    float* qkv   = (float*)p;  p += 196608 * 4;
    float* lnx   = (float*)p;  p += 65536 * 4;
    float* x1    = (float*)p;  p += 65536 * 4;
    float* x2    = (float*)p;  p += 65536 * 4;
    float* qn32  = (float*)p;  p += 65536 * 4;

    // ---- one-time prep ----
    SwzDesc sd;
    const float* srcs[11] = {motion_w1, type_w1, attr_w1, fmlp_w1, fmlp_w2,
                             sa_in_w, sa_out_w, fa_in_w, fa_out_w, ffn_w1, ffn_w2};
    int Ks[11]    = {512, 512, 512, 256, 512, 512, 512, 512, 512, 512, 2048};
    int tiles[11] = {512, 512, 512, 256, 512, 9216, 3072, 9216, 3072, 12288, 12288};
    unsigned int cum = 0;
    for (int i = 0; i < 11; i++) {
        sd.src[i] = srcs[i]; sd.K[i] = Ks[i]; sd.tileStart[i] = cum; cum += tiles[i];
    }
    sd.tileStart[11] = cum;   // 51456

    transpose_feat_k<<<dim3(180, 8, 6), dim3(32, 8), 0, stream>>>(features, feat_t);
    swizzle_w_k<<<51456, 64, 0, stream>>>(sd, swz);
    cvt16_k<<<256, 256, 0, stream>>>(queries0, q016, 65536);

    // swizzled weight bases (halfs)
    const h16* sw_heads = swz;                      // motion|type|attr, N=1536,K=512
    const h16* sw_fmlp1 = swz + 786432;             // K=256
    const h16* sw_fmlp2 = swz + 917504;
    const h16* sw_sain  = swz + 1179648;            // + i*786432
    const h16* sw_saout = swz + 5898240;            // + i*262144
    const h16* sw_fain  = swz + 7471104;            // + i*786432
    const h16* sw_faout = swz + 12189696;           // + i*262144
    const h16* sw_ffn1  = swz + 13762560;           // + i*1048576
    const h16* sw_ffn2  = swz + 20054016;           // + i*1048576

    const h16*   q16 = q016;
    const float* q32 = queries0;

    for (int i = 0; i < 6; i++) {
        // prediction heads
        gemm_swz<2, 1, false, false><<<dim3(48, 8), 64, 0, stream>>>(
            q16, 512, 0, nullptr, nullptr, nullptr, nullptr, nullptr, 0,
            sw_heads, motion_b1, type_b1, attr_b1, nullptr, 0,
            nullptr, hid16, 1536, 512, 1);
        heads2_k<<<dim3(128, 24), 64, 0, stream>>>(hid16, motion_w2, motion_b2,
                                                   type_w2, type_b2, attr_w2, attr_b2,
                                                   pmin, pmax, out + i * 3072);
        if (i == 5) break;

        // feature gather + feature MLP
        gather_k<<<dim3(128, 6), 256, 0, stream>>>(feat_t, proj, out + i * 3072, agg16);
        gemm_swz<1, 6, false, false><<<dim3(32, 8), 64, 0, stream>>>(
            agg16, 256, 32768, nullptr, nullptr, nullptr, nullptr, nullptr, 0,
            sw_fmlp1, fmlp_b1, nullptr, nullptr, nullptr, 0,
            nullptr, fmlph16, 512, 256, 1);
        gemm_swz<1, 1, false, false><<<dim3(32, 8), 64, 0, stream>>>(
            fmlph16, 512, 0, nullptr, nullptr, nullptr, nullptr, nullptr, 0,
            sw_fmlp2, fmlp_b2, nullptr, nullptr, nullptr, 0,
            nullptr, feath16, 512, 512, 0);

        // self-attention (LN1 fused into qkv projection)
        gemm_swz<2, 1, false, true><<<dim3(48, 8), 64, 0, stream>>>(
            nullptr, 0, 0, q32, ln1_g + i * 512, ln1_b + i * 512, lnx, nullptr, 0,
            sw_sain + (size_t)i * 786432, sa_in_b + i * 1536, nullptr, nullptr,
            nullptr, 0, qkv, nullptr, 1536, 512, 0);
        attn_k<<<32, 256, 0, stream>>>(qkv, attnb16);
        gemm_swz<1, 1, false, false><<<dim3(32, 8), 64, 0, stream>>>(
            attnb16, 512, 0, nullptr, nullptr, nullptr, nullptr, nullptr, 0,
            sw_saout + (size_t)i * 262144, sa_out_b + i * 512, nullptr, nullptr,
            lnx, 512, x1, nullptr, 512, 512, 0);

        // cross-attention (LN2 fused; kv side reads feath16 via A2 switch)
        gemm_swz<2, 1, true, true><<<dim3(48, 8), 64, 0, stream>>>(
            nullptr, 0, 0, x1, ln2_g + i * 512, ln2_b + i * 512, lnx, feath16, 16,
            sw_fain + (size_t)i * 786432, fa_in_b + i * 1536, nullptr, nullptr,
            nullptr, 0, qkv, nullptr, 1536, 512, 0);
        attn_k<<<32, 256, 0, stream>>>(qkv, attnb16);
        gemm_swz<1, 1, false, false><<<dim3(32, 8), 64, 0, stream>>>(
            attnb16, 512, 0, nullptr, nullptr, nullptr, nullptr, nullptr, 0,
            sw_faout + (size_t)i * 262144, fa_out_b + i * 512, nullptr, nullptr,
            lnx, 512, x2, nullptr, 512, 512, 0);

        // FFN (LN3 fused into ffn1)
        gemm_swz<2, 1, false, true><<<dim3(64, 8), 64, 0, stream>>>(
            nullptr, 0, 0, x2, ln3_g + i * 512, ln3_b + i * 512, lnx, nullptr, 0,
            sw_ffn1 + (size_t)i * 1048576, ffn_b1 + i * 2048, nullptr, nullptr,
            nullptr, 0, nullptr, ffnh16, 2048, 512, 1);
        gemm_swz<1, 1, false, false><<<dim3(32, 8), 64, 0, stream>>>(
            ffnh16, 2048, 0, nullptr, nullptr, nullptr, nullptr, nullptr, 0,
            sw_ffn2 + (size_t)i * 1048576, ffn_b2 + i * 512, nullptr, nullptr,
            lnx, 512, qn32, qn16, 512, 2048, 0);

        q16 = qn16;
        q32 = qn32;
    }
}

// Round 7
// 866.809 us; speedup vs baseline: 3.6790x; 1.3389x over previous
//
#include <hip/hip_runtime.h>
#include <hip/hip_bf16.h>

typedef __hip_bfloat16 bf16;
typedef _Float16 h16;
typedef __attribute__((ext_vector_type(8))) _Float16 half8;
typedef __attribute__((ext_vector_type(4))) float f32x4;

#define NQ 128
#define HD 512
#define FD 256
#define NC 6
#define IMH 48
#define IMW 120
#define HW 5760   // 48*120

__device__ __forceinline__ half8 pack8(float4 x, float4 y) {
    half8 h;
    h[0] = (h16)x.x; h[1] = (h16)x.y; h[2] = (h16)x.z; h[3] = (h16)x.w;
    h[4] = (h16)y.x; h[5] = (h16)y.y; h[6] = (h16)y.z; h[7] = (h16)y.w;
    return h;
}

// ---------------------------------------------------------------------------
// Transpose features (NC, FD, HW) f32  ->  (NC, HW, FD) bf16
// ---------------------------------------------------------------------------
__global__ __launch_bounds__(256) void transpose_feat_k(const float* __restrict__ f,
                                                        bf16* __restrict__ ft)
{
    __shared__ float tile[32][33];
    int cam = blockIdx.z;
    int hw0 = blockIdx.x * 32, fd0 = blockIdx.y * 32;
    int tx = threadIdx.x, ty = threadIdx.y;
    const float* fb = f + (size_t)cam * FD * HW;
    for (int r = ty; r < 32; r += 8)
        tile[r][tx] = fb[(size_t)(fd0 + r) * HW + hw0 + tx];
    __syncthreads();
    bf16* fo = ft + (size_t)cam * HW * FD;
    for (int r = ty; r < 32; r += 8)
        fo[(size_t)(hw0 + r) * FD + fd0 + tx] = __float2bfloat16(tile[tx][r]);
}

// fp32 -> fp16 copy (queries0)
__global__ __launch_bounds__(256) void cvt16_k(const float* __restrict__ src,
                                               h16* __restrict__ dst, int n)
{
    int i = blockIdx.x * 256 + threadIdx.x;
    if (i < n) dst[i] = (h16)src[i];
}

// ---------------------------------------------------------------------------
// Weight swizzle v2 (coalesced): fp32 row-major -> fp16 MFMA B-fragment tiles.
// Tile (global n-tile tct, ks): lane l holds W[(tct>>2)*64 + (tct&3)*16 + (l&15)]
// [ks*32 + (l>>4)*8 + j], stored 64 lanes x 16B contiguous (1KB).
// dst tile offset = (tileStart[w] + (n64*K32 + ks)*4 + ct) * 512 halfs.
// Each block: one 64-row x 64-col chunk; reads 64B-contiguous per 4-lane
// group, stages fragments in LDS, writes 16KB... (8 tiles x 1KB) coalesced.
// ---------------------------------------------------------------------------
struct SwzDesc {
    const float* src[11];
    unsigned int chunkStart[12];   // block-id boundaries
    unsigned int tileStart[11];    // dst tile base
    int K[11];
};

__global__ __launch_bounds__(256) void swizzle2_k(SwzDesc d, h16* __restrict__ dst)
{
    __shared__ h16 fbuf[4096];     // 8 tiles x 512 halfs
    int bid = blockIdx.x;
    int w = 0;
    while (bid >= (int)d.chunkStart[w + 1]) w++;
    int local = bid - (int)d.chunkStart[w];
    int Kk = d.K[w];
    int kc = Kk >> 6;              // 64-col chunks per row group
    int n64 = local / kc, kchunk = local - n64 * kc;
    int t = threadIdx.x;
    int r = t >> 2, q = t & 3;     // row 0..63, quad 0..3
    int ct = r >> 4, lr = r & 15;
    const float* srow = d.src[w] + (size_t)(n64 * 64 + r) * Kk + kchunk * 64;
#pragma unroll
    for (int p = 0; p < 4; p++) {
        int c = (q + p * 4) * 4;   // 0..60, 4 floats
        float4 u = *(const float4*)(srow + c);
        int ksl = c >> 5, kk = c & 31;
        h16* fp = &fbuf[(size_t)(((ksl * 4 + ct) * 64) + (kk >> 3) * 16 + lr) * 8 + (kk & 7)];
        fp[0] = (h16)u.x; fp[1] = (h16)u.y; fp[2] = (h16)u.z; fp[3] = (h16)u.w;
    }
    __syncthreads();
    int K32 = Kk >> 5;
#pragma unroll
    for (int i = 0; i < 2; i++) {
        int hidx = t + i * 256;            // 16B chunk id, 0..511
        int tl = hidx >> 6, within = hidx & 63;
        int ksl = tl >> 2, ctt = tl & 3;
        size_t tileg = (size_t)d.tileStart[w]
                     + ((size_t)n64 * K32 + (kchunk * 2 + ksl)) * 4 + ctt;
        *(half8*)(dst + tileg * 512 + within * 8) = *(const half8*)&fbuf[tl * 512 + within * 8];
    }
}

// ---------------------------------------------------------------------------
// Split-K-in-block MFMA GEMM on swizzled fp16 weights. 256 thr = 4 waves;
// wave w computes K-quarter w of the same (m0, n-group) tile(s); LDS-combined
// (no atomics). grid (N/(16*CTN), M/16).
// A: fp16 row-major (NSUM slabs summed) or fp32 + fused LayerNorm (LNA).
// A2SW: blocks bx>=a2Start read A2 (fp16, no LN) -- merged cross-attn q/kv.
// LNA && bx==0: wave w also writes its normalized K-quarter to lnout.
// ---------------------------------------------------------------------------
template<int CTN, int NSUM, bool A2SW, bool LNA>
__global__ __launch_bounds__(256) void gemm_sk4(
    const h16* __restrict__ A16, int lda, int sumStride,
    const float* __restrict__ A32,
    const float* __restrict__ lng, const float* __restrict__ lnb,
    float* __restrict__ lnout,
    const h16* __restrict__ A2_16, int a2Start,
    const h16* __restrict__ Wswz,
    const float* __restrict__ B0, const float* __restrict__ B1, const float* __restrict__ B2s,
    const float* __restrict__ R, int ldr,
    float* __restrict__ C32, h16* __restrict__ C16, int ldc,
    int K, int act)
{
    __shared__ float redu[CTN * 4 * 256];
    __shared__ float sst[64], sst2[64];
    int bx = blockIdx.x, by = blockIdx.y;
    int tid = threadIdx.x;
    int w = tid >> 6, l = tid & 63;
    int lr = l & 15, q4 = l >> 4;
    int m0 = by * 16;
    int n0 = bx * 16 * CTN;
    int row = m0 + lr;
    int K32 = K >> 5;
    int KQ = K32 >> 2;
    int ks0 = w * KQ;

    bool useA2 = A2SW && (bx >= a2Start);

    const float* arow32 = nullptr;
    float mean = 0.f, rstd = 1.f;
    if (LNA && !useA2) {
        arow32 = A32 + (size_t)row * K + q4 * 8;
        float s = 0.f, s2 = 0.f;
        for (int ks = ks0; ks < ks0 + KQ; ks++) {
            float4 u = *(const float4*)(arow32 + ks * 32);
            float4 v = *(const float4*)(arow32 + ks * 32 + 4);
            s  += u.x + u.y + u.z + u.w + v.x + v.y + v.z + v.w;
            s2 += u.x*u.x + u.y*u.y + u.z*u.z + u.w*u.w
                + v.x*v.x + v.y*v.y + v.z*v.z + v.w*v.w;
        }
        s  += __shfl_xor(s, 16);  s  += __shfl_xor(s, 32);
        s2 += __shfl_xor(s2, 16); s2 += __shfl_xor(s2, 32);
        if (q4 == 0) { sst[w * 16 + lr] = s; sst2[w * 16 + lr] = s2; }
        __syncthreads();
        float st = sst[lr] + sst[16 + lr] + sst[32 + lr] + sst[48 + lr];
        float st2 = sst2[lr] + sst2[16 + lr] + sst2[32 + lr] + sst2[48 + lr];
        mean = st * (1.0f / (float)K);
        float var = st2 * (1.0f / (float)K) - mean * mean;
        rstd = rsqrtf(var + 1e-5f);
    }

    const h16* arow16 = nullptr;
    if (useA2)       arow16 = A2_16 + (size_t)row * 512 + q4 * 8;
    else if (!LNA)   arow16 = A16 + (size_t)row * lda + q4 * 8;

    // hoisted B fragment bases: per ct, address = base + ks * 2048 halfs
    const h16* wbase[CTN];
#pragma unroll
    for (int ct = 0; ct < CTN; ct++) {
        int tct = (n0 >> 4) + ct;
        wbase[ct] = Wswz + (((size_t)(tct >> 2) * K32 * 4 + (tct & 3)) * 64 + l) * 8;
    }

    f32x4 acc[CTN];
#pragma unroll
    for (int ct = 0; ct < CTN; ct++) acc[ct] = (f32x4){0.f, 0.f, 0.f, 0.f};

    bool wrln = LNA && !useA2 && (bx == 0) && lnout;

#pragma unroll 4
    for (int ks = ks0; ks < ks0 + KQ; ks++) {
        half8 a;
        if (LNA && !useA2) {
            float4 u = *(const float4*)(arow32 + ks * 32);
            float4 v = *(const float4*)(arow32 + ks * 32 + 4);
            float4 g0 = *(const float4*)(lng + ks * 32 + q4 * 8);
            float4 g1 = *(const float4*)(lng + ks * 32 + q4 * 8 + 4);
            float4 b0 = *(const float4*)(lnb + ks * 32 + q4 * 8);
            float4 b1 = *(const float4*)(lnb + ks * 32 + q4 * 8 + 4);
            float4 o0, o1;
            o0.x = (u.x - mean) * rstd * g0.x + b0.x;
            o0.y = (u.y - mean) * rstd * g0.y + b0.y;
            o0.z = (u.z - mean) * rstd * g0.z + b0.z;
            o0.w = (u.w - mean) * rstd * g0.w + b0.w;
            o1.x = (v.x - mean) * rstd * g1.x + b1.x;
            o1.y = (v.y - mean) * rstd * g1.y + b1.y;
            o1.z = (v.z - mean) * rstd * g1.z + b1.z;
            o1.w = (v.w - mean) * rstd * g1.w + b1.w;
            if (wrln) {
                *(float4*)(lnout + (size_t)row * K + ks * 32 + q4 * 8)     = o0;
                *(float4*)(lnout + (size_t)row * K + ks * 32 + q4 * 8 + 4) = o1;
            }
            a = pack8(o0, o1);
        } else if (NSUM == 1) {
            a = *(const half8*)(arow16 + (size_t)ks * 32);
        } else {
            float s[8] = {0.f, 0.f, 0.f, 0.f, 0.f, 0.f, 0.f, 0.f};
#pragma unroll
            for (int j = 0; j < NSUM; j++) {
                half8 tt = *(const half8*)(arow16 + (size_t)j * sumStride + ks * 32);
#pragma unroll
                for (int e = 0; e < 8; e++) s[e] += (float)tt[e];
            }
#pragma unroll
            for (int e = 0; e < 8; e++) a[e] = (h16)s[e];
        }
#pragma unroll
        for (int ct = 0; ct < CTN; ct++) {
            half8 bfr = *(const half8*)(wbase[ct] + (size_t)ks * 2048);
            acc[ct] = __builtin_amdgcn_mfma_f32_16x16x32_f16(a, bfr, acc[ct], 0, 0, 0);
        }
    }

#pragma unroll
    for (int ct = 0; ct < CTN; ct++)
        *(f32x4*)&redu[(size_t)(w * CTN + ct) * 256 + l * 4] = acc[ct];
    __syncthreads();

    if (w < CTN) {
        int ct = w;
        f32x4 sum = *(const f32x4*)&redu[(size_t)ct * 256 + l * 4];
#pragma unroll
        for (int w2 = 1; w2 < 4; w2++) {
            f32x4 tt = *(const f32x4*)&redu[(size_t)(w2 * CTN + ct) * 256 + l * 4];
            sum[0] += tt[0]; sum[1] += tt[1]; sum[2] += tt[2]; sum[3] += tt[3];
        }
        int n = n0 + ct * 16 + lr;
        float bv;
        if (B1) { int sec = n >> 9, ni = n & 511;
                  bv = (sec == 0) ? B0[ni] : (sec == 1 ? B1[ni] : B2s[ni]); }
        else bv = B0[n];
#pragma unroll
        for (int r = 0; r < 4; r++) {
            int m = m0 + q4 * 4 + r;
            float v = sum[r] + bv;
            if (act) v = fmaxf(v, 0.f);
            if (R) v += R[(size_t)m * ldr + n];
            if (C32) C32[(size_t)m * ldc + n] = v;
            if (C16) C16[(size_t)m * ldc + n] = (h16)v;
        }
    }
}

// ---------------------------------------------------------------------------
// Head output: out[q][n] = act( hid16_row . w2_row + b ), into d_out.
// ---------------------------------------------------------------------------
__global__ __launch_bounds__(64) void heads2_k(const h16* __restrict__ hid16,
                                               const float* __restrict__ w2m, const float* __restrict__ b2m,
                                               const float* __restrict__ w2t, const float* __restrict__ b2t,
                                               const float* __restrict__ w2a, const float* __restrict__ b2a,
                                               const float* __restrict__ pmin, const float* __restrict__ pmax,
                                               float* __restrict__ out)
{
    int q = blockIdx.x, n = blockIdx.y, lane = threadIdx.x;
    const float* wr; float bv; int mode, sect;
    if (n < 11)      { sect = 0; wr = w2m + n * 512;        bv = b2m[n];      mode = 0; }
    else if (n < 21) { sect = 1; wr = w2t + (n - 11) * 512; bv = b2t[n - 11]; mode = 1; }
    else             { sect = 2; wr = w2a + (n - 21) * 512; bv = b2a[n - 21]; mode = 2; }
    half8 hv = *(const half8*)(hid16 + q * 1536 + sect * 512 + lane * 8);
    const float4* w4 = (const float4*)(wr + lane * 8);
    float4 c0 = w4[0], c1 = w4[1];
    float acc = (float)hv[0] * c0.x + (float)hv[1] * c0.y
              + (float)hv[2] * c0.z + (float)hv[3] * c0.w
              + (float)hv[4] * c1.x + (float)hv[5] * c1.y
              + (float)hv[6] * c1.z + (float)hv[7] * c1.w;
    for (int off = 32; off; off >>= 1) acc += __shfl_xor(acc, off);
    if (lane == 0) {
        float v = acc + bv;
        if (mode == 0)      v = (1.0f / (1.0f + __expf(-v))) * (pmax[n] - pmin[n]) + pmin[n];
        else if (mode == 2) v = 1.0f / (1.0f + __expf(-v));
        out[q * 24 + n] = v;
    }
}

// ---------------------------------------------------------------------------
// MHA core on packed qkv (128 x 1536 = [Q|K|V] fp32), fp16 output.
// ---------------------------------------------------------------------------
__global__ __launch_bounds__(256) void attn_k(const float* __restrict__ qkv,
                                              h16* __restrict__ out16)
{
    __shared__ float KVl[128 * 68];
    __shared__ float Ql[32 * 68];
    __shared__ float Pl[32 * 128];
    int h = blockIdx.x >> 2, chunk = blockIdx.x & 3;
    int tid = threadIdx.x;

    for (int l = tid; l < 2048; l += 256) {
        int row = l >> 4, c4 = (l & 15) * 4;
        float4 v = *(const float4*)&qkv[row * 1536 + 512 + h * 64 + c4];
        *(float4*)&KVl[row * 68 + c4] = v;
    }
    for (int l = tid; l < 512; l += 256) {
        int row = l >> 4, c4 = (l & 15) * 4;
        float4 v = *(const float4*)&qkv[(chunk * 32 + row) * 1536 + h * 64 + c4];
        *(float4*)&Ql[row * 68 + c4] = v;
    }
    __syncthreads();

    int w = tid >> 6, j = tid & 63;
    for (int r8 = 0; r8 < 8; r8++) {
        int lr = w * 8 + r8;
        float s0 = 0.f, s1 = 0.f;
#pragma unroll
        for (int k4 = 0; k4 < 64; k4 += 4) {
            float4 qv  = *(const float4*)&Ql[lr * 68 + k4];
            float4 k0v = *(const float4*)&KVl[j * 68 + k4];
            float4 k1v = *(const float4*)&KVl[(j + 64) * 68 + k4];
            s0 += qv.x * k0v.x + qv.y * k0v.y + qv.z * k0v.z + qv.w * k0v.w;
            s1 += qv.x * k1v.x + qv.y * k1v.y + qv.z * k1v.z + qv.w * k1v.w;
        }
        s0 *= 0.125f; s1 *= 0.125f;
        float m = fmaxf(s0, s1);
        for (int off = 32; off; off >>= 1) m = fmaxf(m, __shfl_xor(m, off));
        float e0 = __expf(s0 - m), e1 = __expf(s1 - m);
        float sm = e0 + e1;
        for (int off = 32; off; off >>= 1) sm += __shfl_xor(sm, off);
        float inv = 1.0f / sm;
        Pl[lr * 128 + j]      = e0 * inv;
        Pl[lr * 128 + j + 64] = e1 * inv;
    }
    __syncthreads();

    for (int l = tid; l < 2048; l += 256) {
        int row = l >> 4, c4 = (l & 15) * 4;
        float4 v = *(const float4*)&qkv[row * 1536 + 1024 + h * 64 + c4];
        KVl[(c4 + 0) * 132 + row] = v.x;
        KVl[(c4 + 1) * 132 + row] = v.y;
        KVl[(c4 + 2) * 132 + row] = v.z;
        KVl[(c4 + 3) * 132 + row] = v.w;
    }
    __syncthreads();

    int d = tid & 63, w2 = tid >> 6;
    for (int r8 = 0; r8 < 8; r8++) {
        int lr = w2 * 8 + r8;
        float o = 0.f;
#pragma unroll
        for (int j4 = 0; j4 < 128; j4 += 4) {
            float4 pv = *(const float4*)&Pl[lr * 128 + j4];
            float4 vv = *(const float4*)&KVl[d * 132 + j4];
            o += pv.x * vv.x + pv.y * vv.y + pv.z * vv.z + pv.w * vv.w;
        }
        out16[(chunk * 32 + lr) * 512 + h * 64 + d] = (h16)o;
    }
}

// ---------------------------------------------------------------------------
// Gather: grid (128 queries, 6 cams). Compacted taps; fp16 slab out.
// ---------------------------------------------------------------------------
__device__ __forceinline__ float bflo(unsigned u) {
    union { unsigned i; float f; } c; c.i = u << 16; return c.f;
}
__device__ __forceinline__ float bfhi(unsigned u) {
    union { unsigned i; float f; } c; c.i = u & 0xffff0000u; return c.f;
}

__global__ __launch_bounds__(256) void gather_k(const bf16* __restrict__ ft,
                                                const float* __restrict__ proj,
                                                const float* __restrict__ preds,
                                                h16* __restrict__ agg16)
{
    __shared__ float mo[11];
    __shared__ int   goff[384];
    __shared__ float gw[384];
    __shared__ int   cnt;
    __shared__ float part[8][256];
    int n = blockIdx.x, cam = blockIdx.y, tid = threadIdx.x;
    if (tid == 0) cnt = 0;
    if (tid < 11) mo[tid] = preds[n * 24 + tid];
    __syncthreads();

    if (tid < 96) {
        int p = tid;
        float dd0 = mo[8], dd1 = mo[9], dd2 = mo[10];
        float c0 = mo[0], c1 = mo[1], c2 = mo[2];
        float sy, cy;
        sincosf(mo[7], &sy, &cy);
        int face = p >> 4, axis = face >> 1;
        float sgn = (face & 1) ? 0.5f : -0.5f;
        float offi = -0.4f + (float)((p >> 2) & 3) * (0.8f / 3.0f);
        float offj = -0.4f + (float)(p & 3) * (0.8f / 3.0f);
        float t0, t1, t2;
        if (axis == 0)      { t0 = sgn;  t1 = offi; t2 = offj; }
        else if (axis == 1) { t0 = offi; t1 = sgn;  t2 = offj; }
        else                { t0 = offi; t1 = offj; t2 = sgn;  }
        float px = t0 * dd0, py = t1 * dd1, pz = t2 * dd2;
        float X = px * cy - py * sy + c0;
        float Y = px * sy + py * cy + c1;
        float Z = pz + c2;
        const float* P = proj + cam * 12;
        float cu = P[0] * X + P[1] * Y + P[2] * Z + P[3];
        float cv = P[4] * X + P[5] * Y + P[6] * Z + P[7];
        float cz = P[8] * X + P[9] * Y + P[10] * Z + P[11];
        float zs = (fabsf(cz) > 1e-6f) ? cz : 1e-6f;
        float u = cu / zs, v = cv / zs;
        bool front = cz > 0.0f;
        float u0 = floorf(u), v0 = floorf(v);
        float du = u - u0, dv = v - v0;
        float us[4] = {u0, u0 + 1.0f, u0, u0 + 1.0f};
        float vs[4] = {v0, v0, v0 + 1.0f, v0 + 1.0f};
        float wt[4] = {(1.0f - du) * (1.0f - dv), du * (1.0f - dv),
                       (1.0f - du) * dv, du * dv};
        int   myoff[4]; float myw[4]; int k = 0;
#pragma unroll
        for (int t = 0; t < 4; t++) {
            bool ok = front && (us[t] >= 0.0f) && (us[t] <= 119.0f)
                            && (vs[t] >= 0.0f) && (vs[t] <= 47.0f)
                            && (wt[t] > 0.0f);
            if (ok) {
                myoff[k] = ((int)vs[t] * IMW + (int)us[t]) * FD;
                myw[k]   = wt[t];
                k++;
            }
        }
        if (k) {
            int base = atomicAdd(&cnt, k);
            for (int s = 0; s < k; s++) { goff[base + s] = myoff[s]; gw[base + s] = myw[s]; }
        }
    }
    __syncthreads();
    int C = cnt;
    h16* slab = agg16 + (size_t)cam * 32768 + n * 256;
    if (C == 0) { slab[tid] = (h16)0.f; return; }

    int g8  = (tid & 31) * 8;
    int row = tid >> 5;
    const bf16* fb = ft + (size_t)cam * HW * FD + g8;
    float acc[8] = {0.f, 0.f, 0.f, 0.f, 0.f, 0.f, 0.f, 0.f};
    for (int e = row; e < C; e += 8) {
        float w = gw[e];
        uint4 rv = *(const uint4*)(fb + goff[e]);
        acc[0] += w * bflo(rv.x); acc[1] += w * bfhi(rv.x);
        acc[2] += w * bflo(rv.y); acc[3] += w * bfhi(rv.y);
        acc[4] += w * bflo(rv.z); acc[5] += w * bfhi(rv.z);
        acc[6] += w * bflo(rv.w); acc[7] += w * bfhi(rv.w);
    }
#pragma unroll
    for (int j = 0; j < 8; j++) part[row][g8 + j] = acc[j];
    __syncthreads();
    float s = 0.f;
#pragma unroll
    for (int r = 0; r < 8; r++) s += part[r][tid];
    slab[tid] = (h16)(s * (1.0f / 576.0f));
}

// ---------------------------------------------------------------------------
extern "C" void kernel_launch(void* const* d_in, const int* in_sizes, int n_in,
                              void* d_out, int out_size, void* d_ws, size_t ws_size,
                              hipStream_t stream)
{
    const float* features  = (const float*)d_in[0];
    const float* proj      = (const float*)d_in[1];
    const float* queries0  = (const float*)d_in[3];
    const float* pmin      = (const float*)d_in[4];
    const float* pmax      = (const float*)d_in[5];
    const float* motion_w1 = (const float*)d_in[6];
    const float* motion_b1 = (const float*)d_in[7];
    const float* motion_w2 = (const float*)d_in[8];
    const float* motion_b2 = (const float*)d_in[9];
    const float* type_w1   = (const float*)d_in[10];
    const float* type_b1   = (const float*)d_in[11];
    const float* type_w2   = (const float*)d_in[12];
    const float* type_b2   = (const float*)d_in[13];
    const float* attr_w1   = (const float*)d_in[14];
    const float* attr_b1   = (const float*)d_in[15];
    const float* attr_w2   = (const float*)d_in[16];
    const float* attr_b2   = (const float*)d_in[17];
    const float* fmlp_w1   = (const float*)d_in[18];
    const float* fmlp_b1   = (const float*)d_in[19];
    const float* fmlp_w2   = (const float*)d_in[20];
    const float* fmlp_b2   = (const float*)d_in[21];
    const float* sa_in_w   = (const float*)d_in[22];
    const float* sa_in_b   = (const float*)d_in[23];
    const float* sa_out_w  = (const float*)d_in[24];
    const float* sa_out_b  = (const float*)d_in[25];
    const float* fa_in_w   = (const float*)d_in[26];
    const float* fa_in_b   = (const float*)d_in[27];
    const float* fa_out_w  = (const float*)d_in[28];
    const float* fa_out_b  = (const float*)d_in[29];
    const float* ffn_w1    = (const float*)d_in[30];
    const float* ffn_b1    = (const float*)d_in[31];
    const float* ffn_w2    = (const float*)d_in[32];
    const float* ffn_b2    = (const float*)d_in[33];
    const float* ln1_g     = (const float*)d_in[34];
    const float* ln1_b     = (const float*)d_in[35];
    const float* ln2_g     = (const float*)d_in[36];
    const float* ln2_b     = (const float*)d_in[37];
    const float* ln3_g     = (const float*)d_in[38];
    const float* ln3_b     = (const float*)d_in[39];
    float* out = (float*)d_out;

    // ---- workspace ----
    char* p = (char*)d_ws;
    bf16* feat_t = (bf16*)p;   p += (size_t)NC * HW * FD * 2;        // 17.7 MB
    h16* swz     = (h16*)p;    p += (size_t)51456 * 512 * 2;         // 52.7 MB
    h16* q016    = (h16*)p;    p += 65536 * 2;
    h16* hid16   = (h16*)p;    p += 196608 * 2;
    h16* agg16   = (h16*)p;    p += 196608 * 2;
    h16* fmlph16 = (h16*)p;    p += 65536 * 2;
    h16* feath16 = (h16*)p;    p += 65536 * 2;
    h16* attnb16 = (h16*)p;    p += 65536 * 2;
    h16* ffnh16  = (h16*)p;    p += 262144 * 2;
    h16* qn16    = (h16*)p;    p += 65536 * 2;
    float* qkv   = (float*)p;  p += 196608 * 4;
    float* lnx   = (float*)p;  p += 65536 * 4;
    float* x1    = (float*)p;  p += 65536 * 4;
    float* x2    = (float*)p;  p += 65536 * 4;
    float* qn32  = (float*)p;  p += 65536 * 4;

    // ---- one-time prep ----
    SwzDesc sd;
    const float* srcs[11] = {motion_w1, type_w1, attr_w1, fmlp_w1, fmlp_w2,
                             sa_in_w, sa_out_w, fa_in_w, fa_out_w, ffn_w1, ffn_w2};
    int Ks[11]    = {512, 512, 512, 256, 512, 512, 512, 512, 512, 512, 2048};
    int tiles[11] = {512, 512, 512, 256, 512, 9216, 3072, 9216, 3072, 12288, 12288};
    unsigned int cumT = 0, cumC = 0;
    for (int i = 0; i < 11; i++) {
        sd.src[i] = srcs[i]; sd.K[i] = Ks[i];
        sd.tileStart[i] = cumT; sd.chunkStart[i] = cumC;
        cumT += tiles[i]; cumC += tiles[i] >> 3;
    }
    sd.chunkStart[11] = cumC;   // 6432

    swizzle2_k<<<6432, 256, 0, stream>>>(sd, swz);
    cvt16_k<<<256, 256, 0, stream>>>(queries0, q016, 65536);
    transpose_feat_k<<<dim3(180, 8, 6), dim3(32, 8), 0, stream>>>(features, feat_t);

    // swizzled weight bases (halfs)
    const h16* sw_heads = swz;                      // motion|type|attr, N=1536,K=512
    const h16* sw_fmlp1 = swz + 786432;             // K=256
    const h16* sw_fmlp2 = swz + 917504;
    const h16* sw_sain  = swz + 1179648;            // + i*786432
    const h16* sw_saout = swz + 5898240;            // + i*262144
    const h16* sw_fain  = swz + 7471104;            // + i*786432
    const h16* sw_faout = swz + 12189696;           // + i*262144
    const h16* sw_ffn1  = swz + 13762560;           // + i*1048576
    const h16* sw_ffn2  = swz + 20054016;           // + i*1048576

    const h16*   q16 = q016;
    const float* q32 = queries0;

    for (int i = 0; i < 6; i++) {
        // prediction heads
        gemm_sk4<2, 1, false, false><<<dim3(48, 8), 256, 0, stream>>>(
            q16, 512, 0, nullptr, nullptr, nullptr, nullptr, nullptr, 0,
            sw_heads, motion_b1, type_b1, attr_b1, nullptr, 0,
            nullptr, hid16, 1536, 512, 1);
        heads2_k<<<dim3(128, 24), 64, 0, stream>>>(hid16, motion_w2, motion_b2,
                                                   type_w2, type_b2, attr_w2, attr_b2,
                                                   pmin, pmax, out + i * 3072);
        if (i == 5) break;

        // feature gather + feature MLP
        gather_k<<<dim3(128, 6), 256, 0, stream>>>(feat_t, proj, out + i * 3072, agg16);
        gemm_sk4<1, 6, false, false><<<dim3(32, 8), 256, 0, stream>>>(
            agg16, 256, 32768, nullptr, nullptr, nullptr, nullptr, nullptr, 0,
            sw_fmlp1, fmlp_b1, nullptr, nullptr, nullptr, 0,
            nullptr, fmlph16, 512, 256, 1);
        gemm_sk4<1, 1, false, false><<<dim3(32, 8), 256, 0, stream>>>(
            fmlph16, 512, 0, nullptr, nullptr, nullptr, nullptr, nullptr, 0,
            sw_fmlp2, fmlp_b2, nullptr, nullptr, nullptr, 0,
            nullptr, feath16, 512, 512, 0);

        // self-attention (LN1 fused into qkv projection)
        gemm_sk4<2, 1, false, true><<<dim3(48, 8), 256, 0, stream>>>(
            nullptr, 0, 0, q32, ln1_g + i * 512, ln1_b + i * 512, lnx, nullptr, 0,
            sw_sain + (size_t)i * 786432, sa_in_b + i * 1536, nullptr, nullptr,
            nullptr, 0, qkv, nullptr, 1536, 512, 0);
        attn_k<<<32, 256, 0, stream>>>(qkv, attnb16);
        gemm_sk4<1, 1, false, false><<<dim3(32, 8), 256, 0, stream>>>(
            attnb16, 512, 0, nullptr, nullptr, nullptr, nullptr, nullptr, 0,
            sw_saout + (size_t)i * 262144, sa_out_b + i * 512, nullptr, nullptr,
            lnx, 512, x1, nullptr, 512, 512, 0);

        // cross-attention (LN2 fused; kv side reads feath16 via A2 switch)
        gemm_sk4<2, 1, true, true><<<dim3(48, 8), 256, 0, stream>>>(
            nullptr, 0, 0, x1, ln2_g + i * 512, ln2_b + i * 512, lnx, feath16, 16,
            sw_fain + (size_t)i * 786432, fa_in_b + i * 1536, nullptr, nullptr,
            nullptr, 0, qkv, nullptr, 1536, 512, 0);
        attn_k<<<32, 256, 0, stream>>>(qkv, attnb16);
        gemm_sk4<1, 1, false, false><<<dim3(32, 8), 256, 0, stream>>>(
            attnb16, 512, 0, nullptr, nullptr, nullptr, nullptr, nullptr, 0,
            sw_faout + (size_t)i * 262144, fa_out_b + i * 512, nullptr, nullptr,
            lnx, 512, x2, nullptr, 512, 512, 0);

        // FFN (LN3 fused into ffn1)
        gemm_sk4<2, 1, false, true><<<dim3(64, 8), 256, 0, stream>>>(
            nullptr, 0, 0, x2, ln3_g + i * 512, ln3_b + i * 512, lnx, nullptr, 0,
            sw_ffn1 + (size_t)i * 1048576, ffn_b1 + i * 2048, nullptr, nullptr,
            nullptr, 0, nullptr, ffnh16, 2048, 512, 1);
        gemm_sk4<1, 1, false, false><<<dim3(32, 8), 256, 0, stream>>>(
            ffnh16, 2048, 0, nullptr, nullptr, nullptr, nullptr, nullptr, 0,
            sw_ffn2 + (size_t)i * 1048576, ffn_b2 + i * 512, nullptr, nullptr,
            lnx, 512, qn32, qn16, 512, 2048, 0);

        q16 = qn16;
        q32 = qn32;
    }
}